// Round 1
// baseline (1154.047 us; speedup 1.0000x reference)
//
#include <hip/hip_runtime.h>
#include <hip/hip_bf16.h>
#include <stdint.h>

typedef __hip_bfloat16 bf16;
typedef __bf16 bf16x8_t __attribute__((ext_vector_type(8)));
typedef float f32x4_t __attribute__((ext_vector_type(4)));

#define GAS __attribute__((address_space(1)))
#define LAS __attribute__((address_space(3)))

__device__ __forceinline__ f32x4_t mfma16(bf16x8_t a, bf16x8_t b, f32x4_t c) {
    return __builtin_amdgcn_mfma_f32_16x16x32_bf16(a, b, c, 0, 0, 0);
}

// global -> LDS async copy, 16B per lane. lds dest must be wave-uniform base;
// HW writes base + lane*16.
__device__ __forceinline__ void gload_lds16(const void* g, void* l) {
    __builtin_amdgcn_global_load_lds((const GAS void*)g, (LAS void*)l, 16, 0, 0);
}

// ---------------------------------------------------------------- cast fp32->bf16
__global__ __launch_bounds__(256) void cast_f32_bf16(const float* __restrict__ in,
                                                     bf16* __restrict__ out, int n4) {
    int stride = gridDim.x * blockDim.x;
    for (int i = blockIdx.x * blockDim.x + threadIdx.x; i < n4; i += stride) {
        float4 f = reinterpret_cast<const float4*>(in)[i];
        bf16 h0 = __float2bfloat16(f.x), h1 = __float2bfloat16(f.y);
        bf16 h2 = __float2bfloat16(f.z), h3 = __float2bfloat16(f.w);
        ushort4 u;
        u.x = *reinterpret_cast<unsigned short*>(&h0);
        u.y = *reinterpret_cast<unsigned short*>(&h1);
        u.z = *reinterpret_cast<unsigned short*>(&h2);
        u.w = *reinterpret_cast<unsigned short*>(&h3);
        reinterpret_cast<ushort4*>(out)[i] = u;
    }
}

// ---------------------------------------------------------------- NT GEMM
// C[M][N] = A[M][K] @ B[N][K]^T, A,B bf16 row-major, OutT in {bf16, float}.
// 128x128 tile, BK=32, 256 threads (4 waves, 2x2), 16x16x32 bf16 MFMA.
__device__ __forceinline__ void store_out(float* p, float v) { *p = v; }
__device__ __forceinline__ void store_out(bf16* p, float v) { *p = __float2bfloat16(v); }

template <typename OutT>
__global__ __launch_bounds__(256) void gemm_nt(const bf16* __restrict__ A,
                                               const bf16* __restrict__ B,
                                               OutT* __restrict__ C,
                                               int M, int N, int K) {
    __shared__ bf16 As[128 * 32];
    __shared__ bf16 Bs[128 * 32];
    const int t = threadIdx.x;
    const int lane = t & 63;
    const int wv = t >> 6;
    const int wr = wv >> 1, wc = wv & 1;
    const int m0 = blockIdx.y * 128, n0 = blockIdx.x * 128;

    f32x4_t acc[4][4];
#pragma unroll
    for (int i = 0; i < 4; i++)
#pragma unroll
        for (int j = 0; j < 4; j++) acc[i][j] = f32x4_t{0.f, 0.f, 0.f, 0.f};

    const char* Ab = (const char*)A;
    const char* Bb = (const char*)B;
    const int srow = t >> 2;            // staging row within 64-row chunk
    const int scolb = (t & 3) * 16;     // staging byte col (BK=32 -> 64B/row)

    for (int k0 = 0; k0 < K; k0 += 32) {
#pragma unroll
        for (int i = 0; i < 2; ++i) {
            int row = i * 64 + srow;
            gload_lds16(Ab + ((size_t)(m0 + row) * K + k0) * 2 + scolb,
                        (char*)As + (i * 256 + wv * 64) * 16);
            gload_lds16(Bb + ((size_t)(n0 + row) * K + k0) * 2 + scolb,
                        (char*)Bs + (i * 256 + wv * 64) * 16);
        }
        __syncthreads();
        bf16x8_t af[4], bfb[4];
#pragma unroll
        for (int mi = 0; mi < 4; mi++)
            af[mi] = *reinterpret_cast<const bf16x8_t*>(
                (const char*)As + (wr * 64 + mi * 16 + (lane & 15)) * 64 + (lane >> 4) * 16);
#pragma unroll
        for (int ni = 0; ni < 4; ni++)
            bfb[ni] = *reinterpret_cast<const bf16x8_t*>(
                (const char*)Bs + (wc * 64 + ni * 16 + (lane & 15)) * 64 + (lane >> 4) * 16);
#pragma unroll
        for (int mi = 0; mi < 4; mi++)
#pragma unroll
            for (int ni = 0; ni < 4; ni++)
                acc[mi][ni] = mfma16(af[mi], bfb[ni], acc[mi][ni]);
        __syncthreads();
    }

#pragma unroll
    for (int mi = 0; mi < 4; mi++)
#pragma unroll
        for (int ni = 0; ni < 4; ni++)
#pragma unroll
            for (int r = 0; r < 4; r++) {
                int row = m0 + wr * 64 + mi * 16 + ((lane >> 4) << 2) + r;
                int col = n0 + wc * 64 + ni * 16 + (lane & 15);
                store_out(C + (size_t)row * N + col, acc[mi][ni][r]);
            }
}

// ---------------------------------------------------------------- RoPE (+scale on q)
// q,k: [B*T][C] bf16, head-dim D=128, half=64. One thread per (b,t,h,dpair).
__global__ __launch_bounds__(256) void rope_qk(bf16* __restrict__ q, bf16* __restrict__ k,
                                               int total) {
    int idx = blockIdx.x * blockDim.x + threadIdx.x;
    if (idx >= total) return;
    int d = idx & 63;
    int h = (idx >> 6) & 15;
    int bt = idx >> 10;            // b*T + t
    int tpos = bt & 2047;
    float freq = expf(-0.14391157f * (float)d);   // ln(10000)/64
    float ang = (float)tpos * freq;
    float s, c;
    sincosf(ang, &s, &c);
    size_t base = (size_t)bt * 2048 + h * 128 + d;
    const float scale_q = 0.08838834764831845f;   // 1/sqrt(128)
    {
        float x1 = __bfloat162float(q[base]);
        float x2 = __bfloat162float(q[base + 64]);
        q[base]      = __float2bfloat16((x1 * c - x2 * s) * scale_q);
        q[base + 64] = __float2bfloat16((x1 * s + x2 * c) * scale_q);
    }
    {
        float x1 = __bfloat162float(k[base]);
        float x2 = __bfloat162float(k[base + 64]);
        k[base]      = __float2bfloat16(x1 * c - x2 * s);
        k[base + 64] = __float2bfloat16(x1 * s + x2 * c);
    }
}

// ---------------------------------------------------------------- V transpose
// v: [B*T][C] -> vT: [B*H][D][T]
__global__ __launch_bounds__(256) void transpose_v(const bf16* __restrict__ v,
                                                   bf16* __restrict__ vT) {
    __shared__ bf16 tile[64][65];
    const int T = 2048, Cc = 2048;
    int bh = blockIdx.z, b = bh >> 4, h = bh & 15;
    int t0 = blockIdx.x * 64, d0 = blockIdx.y * 64;
    int tx = threadIdx.x & 63, ty = threadIdx.x >> 6;
#pragma unroll
    for (int i = 0; i < 16; i++) {
        int tt = ty + i * 4;
        tile[tt][tx] = v[(size_t)(b * T + t0 + tt) * Cc + h * 128 + d0 + tx];
    }
    __syncthreads();
#pragma unroll
    for (int i = 0; i < 16; i++) {
        int dd = ty + i * 4;
        vT[(size_t)(bh * 128 + d0 + dd) * T + t0 + tx] = tile[tx][dd];
    }
}

// ---------------------------------------------------------------- flash attention
// q,k: [B*T][C] bf16 (rope'd, q pre-scaled). vT: [B*H][D][T]. att out: [B*T][C] bf16.
// grid: (T/64, B*H). 256 threads = 4 waves, each wave owns 16 q rows.
__global__ __launch_bounds__(256) void flash_attn(const bf16* __restrict__ q,
                                                  const bf16* __restrict__ k,
                                                  const bf16* __restrict__ vT,
                                                  bf16* __restrict__ att) {
    const int T = 2048, Cc = 2048;
    __shared__ bf16 Ks[64 * 128];    // [kv row][d]
    __shared__ bf16 VTs[128 * 64];   // [d][kv row]
    __shared__ bf16 Ps[4][16 * 64];  // per-wave P tile
    const int t = threadIdx.x, lane = t & 63, w = t >> 6;
    const int bh = blockIdx.y, b = bh >> 4, h = bh & 15;
    const int q0 = blockIdx.x * 64;

    // Q fragments stay in registers: A-operand layout (row=lane&15, k contiguous)
    bf16x8_t qf[4];
    {
        int qrow = q0 + w * 16 + (lane & 15);
        const char* qb = (const char*)q + ((size_t)(b * T + qrow) * Cc + h * 128) * 2;
#pragma unroll
        for (int kf = 0; kf < 4; kf++)
            qf[kf] = *reinterpret_cast<const bf16x8_t*>(qb + kf * 64 + (lane >> 4) * 16);
    }

    f32x4_t acc[8];
#pragma unroll
    for (int i = 0; i < 8; i++) acc[i] = f32x4_t{0.f, 0.f, 0.f, 0.f};
    float m_run[4] = {-1e30f, -1e30f, -1e30f, -1e30f};
    float l_run[4] = {0.f, 0.f, 0.f, 0.f};

    const int ntiles = blockIdx.x + 1;  // causal
    for (int ti = 0; ti < ntiles; ++ti) {
        const int k0 = ti * 64;
#pragma unroll
        for (int i = 0; i < 4; ++i) {
            int o = (i * 256 + t) * 16;
            gload_lds16((const char*)k + ((size_t)(b * T + k0 + (o >> 8)) * Cc + h * 128) * 2 + (o & 255),
                        (char*)Ks + (i * 256 + w * 64) * 16);
            gload_lds16((const char*)vT + ((size_t)(bh * 128 + (o >> 7)) * T + k0) * 2 + (o & 127),
                        (char*)VTs + (i * 256 + w * 64) * 16);
        }
        __syncthreads();

        // S = q @ k^T  (16 rows x 64 cols per wave)
        f32x4_t s[4];
#pragma unroll
        for (int nb = 0; nb < 4; nb++) {
            s[nb] = f32x4_t{0.f, 0.f, 0.f, 0.f};
#pragma unroll
            for (int kf = 0; kf < 4; kf++) {
                bf16x8_t kfr = *reinterpret_cast<const bf16x8_t*>(
                    (const char*)Ks + (nb * 16 + (lane & 15)) * 256 + kf * 64 + (lane >> 4) * 16);
                s[nb] = mfma16(qf[kf], kfr, s[nb]);
            }
        }

        // causal mask + online softmax
        const int col = lane & 15;
        const int rowb = q0 + w * 16 + ((lane >> 4) << 2);
        float mt[4] = {-1e30f, -1e30f, -1e30f, -1e30f};
#pragma unroll
        for (int nb = 0; nb < 4; nb++) {
            int kc = k0 + nb * 16 + col;
#pragma unroll
            for (int r = 0; r < 4; r++) {
                float v = s[nb][r];
                if (kc > rowb + r) v = -1e30f;
                s[nb][r] = v;
                mt[r] = fmaxf(mt[r], v);
            }
        }
#pragma unroll
        for (int r = 0; r < 4; r++) {
#pragma unroll
            for (int mk = 1; mk < 16; mk <<= 1)
                mt[r] = fmaxf(mt[r], __shfl_xor(mt[r], mk, 64));
        }
        float alpha[4], ls[4];
#pragma unroll
        for (int r = 0; r < 4; r++) {
            float mn = fmaxf(m_run[r], mt[r]);
            alpha[r] = __expf(m_run[r] - mn);
            m_run[r] = mn;
            ls[r] = 0.f;
        }
#pragma unroll
        for (int nb = 0; nb < 4; nb++)
#pragma unroll
            for (int r = 0; r < 4; r++) {
                float p = __expf(s[nb][r] - m_run[r]);
                s[nb][r] = p;
                ls[r] += p;
            }
#pragma unroll
        for (int r = 0; r < 4; r++) {
#pragma unroll
            for (int mk = 1; mk < 16; mk <<= 1)
                ls[r] += __shfl_xor(ls[r], mk, 64);
            l_run[r] = l_run[r] * alpha[r] + ls[r];
        }
#pragma unroll
        for (int i = 0; i < 8; i++)
#pragma unroll
            for (int r = 0; r < 4; r++) acc[i][r] *= alpha[r];

        // P (C/D layout) -> LDS -> A-operand layout
#pragma unroll
        for (int nb = 0; nb < 4; nb++)
#pragma unroll
            for (int r = 0; r < 4; r++)
                Ps[w][(((lane >> 4) << 2) + r) * 64 + nb * 16 + col] =
                    __float2bfloat16(s[nb][r]);
        asm volatile("s_waitcnt lgkmcnt(0)" ::: "memory");
        bf16x8_t pf[2];
#pragma unroll
        for (int kb = 0; kb < 2; kb++)
            pf[kb] = *reinterpret_cast<const bf16x8_t*>(
                (const char*)Ps[w] + (lane & 15) * 128 + kb * 64 + (lane >> 4) * 16);

        // O += P @ V
#pragma unroll
        for (int db = 0; db < 8; db++)
#pragma unroll
            for (int kb = 0; kb < 2; kb++) {
                bf16x8_t vf = *reinterpret_cast<const bf16x8_t*>(
                    (const char*)VTs + (db * 16 + (lane & 15)) * 128 + kb * 64 + (lane >> 4) * 16);
                acc[db] = mfma16(pf[kb], vf, acc[db]);
            }
        __syncthreads();
    }

    // epilogue: normalize + write
#pragma unroll
    for (int r = 0; r < 4; r++) {
        float inv = 1.0f / l_run[r];
        int row = q0 + w * 16 + ((lane >> 4) << 2) + r;
        size_t base = (size_t)(b * T + row) * Cc + h * 128;
#pragma unroll
        for (int db = 0; db < 8; db++)
            att[base + db * 16 + (lane & 15)] = __float2bfloat16(acc[db][r] * inv);
    }
}

// ---------------------------------------------------------------- launcher
extern "C" void kernel_launch(void* const* d_in, const int* in_sizes, int n_in,
                              void* d_out, int out_size, void* d_ws, size_t ws_size,
                              hipStream_t stream) {
    const int B = 4, T = 2048, C = 2048;
    const int M = B * T;  // 8192
    const float* x  = (const float*)d_in[0];
    const float* wq = (const float*)d_in[1];
    const float* wk = (const float*)d_in[2];
    const float* wv = (const float*)d_in[3];
    const float* wo = (const float*)d_in[4];
    float* out = (float*)d_out;

    char* ws = (char*)d_ws;
    const size_t SZ_X = (size_t)M * C * 2;       // 33554432
    const size_t SZ_W = (size_t)C * C * 2;       // 8388608
    bf16* xb   = (bf16*)(ws);
    bf16* wqb  = (bf16*)(ws + SZ_X);
    bf16* wkb  = (bf16*)(ws + SZ_X + SZ_W);
    bf16* wvb  = (bf16*)(ws + SZ_X + 2 * SZ_W);
    bf16* wob  = (bf16*)(ws + SZ_X + 3 * SZ_W);
    bf16* qb   = (bf16*)(ws + SZ_X + 4 * SZ_W);
    bf16* kb   = (bf16*)(ws + 2 * SZ_X + 4 * SZ_W);
    bf16* vb   = (bf16*)(ws + 3 * SZ_X + 4 * SZ_W);
    bf16* vTb  = (bf16*)(ws + 4 * SZ_X + 4 * SZ_W);
    bf16* attb = (bf16*)(ws + 5 * SZ_X + 4 * SZ_W);

    // 1) casts
    cast_f32_bf16<<<2048, 256, 0, stream>>>(x, xb, M * C / 4);
    cast_f32_bf16<<<1024, 256, 0, stream>>>(wq, wqb, C * C / 4);
    cast_f32_bf16<<<1024, 256, 0, stream>>>(wk, wkb, C * C / 4);
    cast_f32_bf16<<<1024, 256, 0, stream>>>(wv, wvb, C * C / 4);
    cast_f32_bf16<<<1024, 256, 0, stream>>>(wo, wob, C * C / 4);

    // 2) QKV projections
    dim3 ggrid(C / 128, M / 128);
    gemm_nt<bf16><<<ggrid, 256, 0, stream>>>(xb, wqb, qb, M, C, C);
    gemm_nt<bf16><<<ggrid, 256, 0, stream>>>(xb, wkb, kb, M, C, C);
    gemm_nt<bf16><<<ggrid, 256, 0, stream>>>(xb, wvb, vb, M, C, C);

    // 3) RoPE + scale
    int rope_total = B * T * 16 * 64;
    rope_qk<<<rope_total / 256, 256, 0, stream>>>(qb, kb, rope_total);

    // 4) V transpose
    transpose_v<<<dim3(T / 64, 2, B * 16), 256, 0, stream>>>(vb, vTb);

    // 5) flash attention
    flash_attn<<<dim3(T / 64, B * 16), 256, 0, stream>>>(qb, kb, vTb, attb);

    // 6) output projection (fp32 out)
    gemm_nt<float><<<ggrid, 256, 0, stream>>>(attb, wob, out, M, C, C);
}

// Round 2
// 817.216 us; speedup vs baseline: 1.4122x; 1.4122x over previous
//
#include <hip/hip_runtime.h>
#include <hip/hip_bf16.h>
#include <stdint.h>

typedef __hip_bfloat16 bf16;
typedef __bf16 bf16x8_t __attribute__((ext_vector_type(8)));
typedef float f32x4_t __attribute__((ext_vector_type(4)));

#define GAS __attribute__((address_space(1)))
#define LAS __attribute__((address_space(3)))

__device__ __forceinline__ f32x4_t mfma16(bf16x8_t a, bf16x8_t b, f32x4_t c) {
    return __builtin_amdgcn_mfma_f32_16x16x32_bf16(a, b, c, 0, 0, 0);
}

// global -> LDS async copy, 16B per lane. lds dest must be wave-uniform base;
// HW writes base + lane*16. Global source IS per-lane -> swizzle there.
__device__ __forceinline__ void gload_lds16(const void* g, void* l) {
    __builtin_amdgcn_global_load_lds((const GAS void*)g, (LAS void*)l, 16, 0, 0);
}

// XOR swizzles: spread column reads of row-major LDS tiles across banks.
// 256B-row tiles (Ks): byte ^= ((row&7)<<4)
__device__ __forceinline__ int swzK(int a) { return a ^ (((a >> 8) & 7) << 4); }
// 128B-row tiles (VTs)
__device__ __forceinline__ int swzV(int a) { return a ^ (((a >> 7) & 7) << 4); }

// ---------------------------------------------------------------- cast fp32->bf16
__global__ __launch_bounds__(256) void cast_f32_bf16(const float* __restrict__ in,
                                                     bf16* __restrict__ out, int n4) {
    int stride = gridDim.x * blockDim.x;
    for (int i = blockIdx.x * blockDim.x + threadIdx.x; i < n4; i += stride) {
        float4 f = reinterpret_cast<const float4*>(in)[i];
        bf16 h0 = __float2bfloat16(f.x), h1 = __float2bfloat16(f.y);
        bf16 h2 = __float2bfloat16(f.z), h3 = __float2bfloat16(f.w);
        ushort4 u;
        u.x = *reinterpret_cast<unsigned short*>(&h0);
        u.y = *reinterpret_cast<unsigned short*>(&h1);
        u.z = *reinterpret_cast<unsigned short*>(&h2);
        u.w = *reinterpret_cast<unsigned short*>(&h3);
        reinterpret_cast<ushort4*>(out)[i] = u;
    }
}

// ---------------------------------------------------------------- NT GEMM
// C[M][N] = A[M][K] @ B[N][K]^T, A,B bf16 row-major, OutT in {bf16, float}.
// 128x128 tile, BK=32, 256 threads (4 waves, 2x2), 16x16x32 bf16 MFMA.
__device__ __forceinline__ void store_out(float* p, float v) { *p = v; }
__device__ __forceinline__ void store_out(bf16* p, float v) { *p = __float2bfloat16(v); }

template <typename OutT>
__global__ __launch_bounds__(256) void gemm_nt(const bf16* __restrict__ A,
                                               const bf16* __restrict__ B,
                                               OutT* __restrict__ C,
                                               int M, int N, int K) {
    __shared__ bf16 As[128 * 32];
    __shared__ bf16 Bs[128 * 32];
    const int t = threadIdx.x;
    const int lane = t & 63;
    const int wv = t >> 6;
    const int wr = wv >> 1, wc = wv & 1;
    const int m0 = blockIdx.y * 128, n0 = blockIdx.x * 128;

    f32x4_t acc[4][4];
#pragma unroll
    for (int i = 0; i < 4; i++)
#pragma unroll
        for (int j = 0; j < 4; j++) acc[i][j] = f32x4_t{0.f, 0.f, 0.f, 0.f};

    const char* Ab = (const char*)A;
    const char* Bb = (const char*)B;
    const int srow = t >> 2;            // staging row within 64-row chunk
    const int scolb = (t & 3) * 16;     // staging byte col (BK=32 -> 64B/row)

    for (int k0 = 0; k0 < K; k0 += 32) {
#pragma unroll
        for (int i = 0; i < 2; ++i) {
            int row = i * 64 + srow;
            gload_lds16(Ab + ((size_t)(m0 + row) * K + k0) * 2 + scolb,
                        (char*)As + (i * 256 + wv * 64) * 16);
            gload_lds16(Bb + ((size_t)(n0 + row) * K + k0) * 2 + scolb,
                        (char*)Bs + (i * 256 + wv * 64) * 16);
        }
        __syncthreads();
        bf16x8_t af[4], bfb[4];
#pragma unroll
        for (int mi = 0; mi < 4; mi++)
            af[mi] = *reinterpret_cast<const bf16x8_t*>(
                (const char*)As + (wr * 64 + mi * 16 + (lane & 15)) * 64 + (lane >> 4) * 16);
#pragma unroll
        for (int ni = 0; ni < 4; ni++)
            bfb[ni] = *reinterpret_cast<const bf16x8_t*>(
                (const char*)Bs + (wc * 64 + ni * 16 + (lane & 15)) * 64 + (lane >> 4) * 16);
#pragma unroll
        for (int mi = 0; mi < 4; mi++)
#pragma unroll
            for (int ni = 0; ni < 4; ni++)
                acc[mi][ni] = mfma16(af[mi], bfb[ni], acc[mi][ni]);
        __syncthreads();
    }

#pragma unroll
    for (int mi = 0; mi < 4; mi++)
#pragma unroll
        for (int ni = 0; ni < 4; ni++)
#pragma unroll
            for (int r = 0; r < 4; r++) {
                int row = m0 + wr * 64 + mi * 16 + ((lane >> 4) << 2) + r;
                int col = n0 + wc * 64 + ni * 16 + (lane & 15);
                store_out(C + (size_t)row * N + col, acc[mi][ni][r]);
            }
}

// ---------------------------------------------------------------- RoPE (+scale on q)
__global__ __launch_bounds__(256) void rope_qk(bf16* __restrict__ q, bf16* __restrict__ k,
                                               int total) {
    int idx = blockIdx.x * blockDim.x + threadIdx.x;
    if (idx >= total) return;
    int d = idx & 63;
    int h = (idx >> 6) & 15;
    int bt = idx >> 10;            // b*T + t
    int tpos = bt & 2047;
    float freq = expf(-0.14391157f * (float)d);   // ln(10000)/64
    float ang = (float)tpos * freq;
    float s, c;
    sincosf(ang, &s, &c);
    size_t base = (size_t)bt * 2048 + h * 128 + d;
    const float scale_q = 0.08838834764831845f;   // 1/sqrt(128)
    {
        float x1 = __bfloat162float(q[base]);
        float x2 = __bfloat162float(q[base + 64]);
        q[base]      = __float2bfloat16((x1 * c - x2 * s) * scale_q);
        q[base + 64] = __float2bfloat16((x1 * s + x2 * c) * scale_q);
    }
    {
        float x1 = __bfloat162float(k[base]);
        float x2 = __bfloat162float(k[base + 64]);
        k[base]      = __float2bfloat16(x1 * c - x2 * s);
        k[base + 64] = __float2bfloat16(x1 * s + x2 * c);
    }
}

// ---------------------------------------------------------------- V transpose
// v: [B*T][C] -> vT: [B*H][D][T]
__global__ __launch_bounds__(256) void transpose_v(const bf16* __restrict__ v,
                                                   bf16* __restrict__ vT) {
    __shared__ bf16 tile[64][65];
    const int T = 2048, Cc = 2048;
    int bh = blockIdx.z, b = bh >> 4, h = bh & 15;
    int t0 = blockIdx.x * 64, d0 = blockIdx.y * 64;
    int tx = threadIdx.x & 63, ty = threadIdx.x >> 6;
#pragma unroll
    for (int i = 0; i < 16; i++) {
        int tt = ty + i * 4;
        tile[tt][tx] = v[(size_t)(b * T + t0 + tt) * Cc + h * 128 + d0 + tx];
    }
    __syncthreads();
#pragma unroll
    for (int i = 0; i < 16; i++) {
        int dd = ty + i * 4;
        vT[(size_t)(bh * 128 + d0 + dd) * T + t0 + tx] = tile[tx][dd];
    }
}

// ---------------------------------------------------------------- flash attention
// q,k: [B*T][C] bf16 (rope'd, q pre-scaled). vT: [B*H][D][T]. att out: [B*T][C] bf16.
// grid: (16 pairs, B*H). Block processes q-blocks {pair, 31-pair}: 33 KV-tiles
// each -> perfect load balance. Ks/VTs XOR-swizzled (linear LDS dest +
// pre-swizzled global source + swizzled reads). Ps padded to stride 72.
__global__ __launch_bounds__(256) void flash_attn(const bf16* __restrict__ q,
                                                  const bf16* __restrict__ k,
                                                  const bf16* __restrict__ vT,
                                                  bf16* __restrict__ att) {
    const int T = 2048, Cc = 2048;
    __shared__ bf16 Ks[64 * 128];    // [kv row][d], 256B rows, swizzled
    __shared__ bf16 VTs[128 * 64];   // [d][kv row], 128B rows, swizzled
    __shared__ bf16 Ps[4][16 * 72];  // per-wave P tile, stride 72 elems (144B)
    const int t = threadIdx.x, lane = t & 63, w = t >> 6;
    const int bh = blockIdx.y, b = bh >> 4, h = bh & 15;
    const int col = lane & 15, hi = lane >> 4;

    for (int pass = 0; pass < 2; ++pass) {
        const int qblk = pass ? (31 - (int)blockIdx.x) : (int)blockIdx.x;
        const int q0 = qblk * 64;

        // Q fragments in registers: A-operand layout (row=lane&15, k contiguous)
        bf16x8_t qf[4];
        {
            int qrow = q0 + w * 16 + col;
            const char* qb = (const char*)q + ((size_t)(b * T + qrow) * Cc + h * 128) * 2;
#pragma unroll
            for (int kf = 0; kf < 4; kf++)
                qf[kf] = *reinterpret_cast<const bf16x8_t*>(qb + kf * 64 + hi * 16);
        }

        f32x4_t acc[8];
#pragma unroll
        for (int i = 0; i < 8; i++) acc[i] = f32x4_t{0.f, 0.f, 0.f, 0.f};
        float m_run[4] = {-1e30f, -1e30f, -1e30f, -1e30f};
        float l_run[4] = {0.f, 0.f, 0.f, 0.f};

        const int ntiles = qblk + 1;  // causal
        for (int ti = 0; ti < ntiles; ++ti) {
            const int k0 = ti * 64;
#pragma unroll
            for (int i = 0; i < 4; ++i) {
                int o = (i * 256 + t) * 16;
                int kr = o >> 8, kc = (o & 255) ^ ((kr & 7) << 4);
                gload_lds16((const char*)k + ((size_t)(b * T + k0 + kr) * Cc + h * 128) * 2 + kc,
                            (char*)Ks + (i * 256 + w * 64) * 16);
                int vr = o >> 7, vc = (o & 127) ^ ((vr & 7) << 4);
                gload_lds16((const char*)vT + ((size_t)(bh * 128 + vr) * T + k0) * 2 + vc,
                            (char*)VTs + (i * 256 + w * 64) * 16);
            }
            __syncthreads();

            // S = q @ k^T  (16 rows x 64 cols per wave)
            f32x4_t s[4];
#pragma unroll
            for (int nb = 0; nb < 4; nb++) {
                s[nb] = f32x4_t{0.f, 0.f, 0.f, 0.f};
#pragma unroll
                for (int kf = 0; kf < 4; kf++) {
                    bf16x8_t kfr = *reinterpret_cast<const bf16x8_t*>(
                        (const char*)Ks + swzK((nb * 16 + col) * 256 + kf * 64 + hi * 16));
                    s[nb] = mfma16(qf[kf], kfr, s[nb]);
                }
            }

            // causal mask + online softmax
            const int rowb = q0 + w * 16 + (hi << 2);
            float mt[4] = {-1e30f, -1e30f, -1e30f, -1e30f};
#pragma unroll
            for (int nb = 0; nb < 4; nb++) {
                int kc = k0 + nb * 16 + col;
#pragma unroll
                for (int r = 0; r < 4; r++) {
                    float v = s[nb][r];
                    if (kc > rowb + r) v = -1e30f;
                    s[nb][r] = v;
                    mt[r] = fmaxf(mt[r], v);
                }
            }
#pragma unroll
            for (int r = 0; r < 4; r++) {
#pragma unroll
                for (int mk = 1; mk < 16; mk <<= 1)
                    mt[r] = fmaxf(mt[r], __shfl_xor(mt[r], mk, 64));
            }
            float alpha[4], ls[4];
#pragma unroll
            for (int r = 0; r < 4; r++) {
                float mn = fmaxf(m_run[r], mt[r]);
                alpha[r] = __expf(m_run[r] - mn);
                m_run[r] = mn;
                ls[r] = 0.f;
            }
#pragma unroll
            for (int nb = 0; nb < 4; nb++)
#pragma unroll
                for (int r = 0; r < 4; r++) {
                    float p = __expf(s[nb][r] - m_run[r]);
                    s[nb][r] = p;
                    ls[r] += p;
                }
#pragma unroll
            for (int r = 0; r < 4; r++) {
#pragma unroll
                for (int mk = 1; mk < 16; mk <<= 1)
                    ls[r] += __shfl_xor(ls[r], mk, 64);
                l_run[r] = l_run[r] * alpha[r] + ls[r];
            }
#pragma unroll
            for (int i = 0; i < 8; i++)
#pragma unroll
                for (int r = 0; r < 4; r++) acc[i][r] *= alpha[r];

            // P (C/D layout) -> LDS (stride 72) -> A-operand layout
#pragma unroll
            for (int nb = 0; nb < 4; nb++)
#pragma unroll
                for (int r = 0; r < 4; r++)
                    Ps[w][((hi << 2) + r) * 72 + nb * 16 + col] =
                        __float2bfloat16(s[nb][r]);
            asm volatile("s_waitcnt lgkmcnt(0)" ::: "memory");
            __builtin_amdgcn_sched_barrier(0);
            bf16x8_t pf[2];
#pragma unroll
            for (int kb = 0; kb < 2; kb++)
                pf[kb] = *reinterpret_cast<const bf16x8_t*>(
                    (const char*)Ps[w] + col * 144 + kb * 64 + hi * 16);

            // O += P @ V
#pragma unroll
            for (int db = 0; db < 8; db++)
#pragma unroll
                for (int kb = 0; kb < 2; kb++) {
                    bf16x8_t vf = *reinterpret_cast<const bf16x8_t*>(
                        (const char*)VTs + swzV((db * 16 + col) * 128 + kb * 64 + hi * 16));
                    acc[db] = mfma16(pf[kb], vf, acc[db]);
                }
            __syncthreads();
        }

        // epilogue: normalize + write (registers + global only; next pass's
        // staging can't race us past the loop-final barrier)
#pragma unroll
        for (int r = 0; r < 4; r++) {
            float inv = 1.0f / l_run[r];
            int row = q0 + w * 16 + (hi << 2) + r;
            size_t base = (size_t)(b * T + row) * Cc + h * 128;
#pragma unroll
            for (int db = 0; db < 8; db++)
                att[base + db * 16 + col] = __float2bfloat16(acc[db][r] * inv);
        }
    }
}

// ---------------------------------------------------------------- launcher
extern "C" void kernel_launch(void* const* d_in, const int* in_sizes, int n_in,
                              void* d_out, int out_size, void* d_ws, size_t ws_size,
                              hipStream_t stream) {
    const int B = 4, T = 2048, C = 2048;
    const int M = B * T;  // 8192
    const float* x  = (const float*)d_in[0];
    const float* wq = (const float*)d_in[1];
    const float* wk = (const float*)d_in[2];
    const float* wv = (const float*)d_in[3];
    const float* wo = (const float*)d_in[4];
    float* out = (float*)d_out;

    char* ws = (char*)d_ws;
    const size_t SZ_X = (size_t)M * C * 2;       // 33554432
    const size_t SZ_W = (size_t)C * C * 2;       // 8388608
    bf16* xb   = (bf16*)(ws);
    bf16* wqb  = (bf16*)(ws + SZ_X);
    bf16* wkb  = (bf16*)(ws + SZ_X + SZ_W);
    bf16* wvb  = (bf16*)(ws + SZ_X + 2 * SZ_W);
    bf16* wob  = (bf16*)(ws + SZ_X + 3 * SZ_W);
    bf16* qb   = (bf16*)(ws + SZ_X + 4 * SZ_W);
    bf16* kb   = (bf16*)(ws + 2 * SZ_X + 4 * SZ_W);
    bf16* vb   = (bf16*)(ws + 3 * SZ_X + 4 * SZ_W);
    bf16* vTb  = (bf16*)(ws + 4 * SZ_X + 4 * SZ_W);
    bf16* attb = (bf16*)(ws + 5 * SZ_X + 4 * SZ_W);

    // 1) casts
    cast_f32_bf16<<<2048, 256, 0, stream>>>(x, xb, M * C / 4);
    cast_f32_bf16<<<1024, 256, 0, stream>>>(wq, wqb, C * C / 4);
    cast_f32_bf16<<<1024, 256, 0, stream>>>(wk, wkb, C * C / 4);
    cast_f32_bf16<<<1024, 256, 0, stream>>>(wv, wvb, C * C / 4);
    cast_f32_bf16<<<1024, 256, 0, stream>>>(wo, wob, C * C / 4);

    // 2) QKV projections
    dim3 ggrid(C / 128, M / 128);
    gemm_nt<bf16><<<ggrid, 256, 0, stream>>>(xb, wqb, qb, M, C, C);
    gemm_nt<bf16><<<ggrid, 256, 0, stream>>>(xb, wkb, kb, M, C, C);
    gemm_nt<bf16><<<ggrid, 256, 0, stream>>>(xb, wvb, vb, M, C, C);

    // 3) RoPE + scale
    int rope_total = B * T * 16 * 64;
    rope_qk<<<rope_total / 256, 256, 0, stream>>>(qb, kb, rope_total);

    // 4) V transpose
    transpose_v<<<dim3(T / 64, 2, B * 16), 256, 0, stream>>>(vb, vTb);

    // 5) flash attention (paired q-blocks: uniform 33 tiles/block)
    flash_attn<<<dim3(16, B * 16), 256, 0, stream>>>(qb, kb, vTb, attb);

    // 6) output projection (fp32 out)
    gemm_nt<float><<<ggrid, 256, 0, stream>>>(attb, wob, out, M, C, C);
}

// Round 4
// 800.205 us; speedup vs baseline: 1.4422x; 1.0213x over previous
//
#include <hip/hip_runtime.h>
#include <hip/hip_bf16.h>
#include <stdint.h>

typedef __hip_bfloat16 bf16;
typedef __bf16 bf16x8_t __attribute__((ext_vector_type(8)));
typedef float f32x4_t __attribute__((ext_vector_type(4)));

#define GAS __attribute__((address_space(1)))
#define LAS __attribute__((address_space(3)))
#define SCHED0 __builtin_amdgcn_sched_barrier(0)

__device__ __forceinline__ f32x4_t mfma16(bf16x8_t a, bf16x8_t b, f32x4_t c) {
    return __builtin_amdgcn_mfma_f32_16x16x32_bf16(a, b, c, 0, 0, 0);
}

// global -> LDS async copy, 16B per lane. LDS dest wave-uniform base + lane*16;
// global source IS per-lane (swizzle there).
__device__ __forceinline__ void gload_lds16(const void* g, void* l) {
    __builtin_amdgcn_global_load_lds((const GAS void*)g, (LAS void*)l, 16, 0, 0);
}

// ---------------------------------------------------------------- cast fp32->bf16
__global__ __launch_bounds__(256) void cast_f32_bf16(const float* __restrict__ in,
                                                     bf16* __restrict__ out, int n4) {
    int stride = gridDim.x * blockDim.x;
    for (int i = blockIdx.x * blockDim.x + threadIdx.x; i < n4; i += stride) {
        float4 f = reinterpret_cast<const float4*>(in)[i];
        bf16 h0 = __float2bfloat16(f.x), h1 = __float2bfloat16(f.y);
        bf16 h2 = __float2bfloat16(f.z), h3 = __float2bfloat16(f.w);
        ushort4 u;
        u.x = *reinterpret_cast<unsigned short*>(&h0);
        u.y = *reinterpret_cast<unsigned short*>(&h1);
        u.z = *reinterpret_cast<unsigned short*>(&h2);
        u.w = *reinterpret_cast<unsigned short*>(&h3);
        reinterpret_cast<ushort4*>(out)[i] = u;
    }
}

// ---------------------------------------------------------------- NT GEMM 256x256
// C[M][N] = A[M][K] @ B[N][K]^T. 256x256 tile, BK=64, 512 thr (8 waves 2Mx4N),
// double-buffered 128KiB LDS, counted vmcnt (never drained in main loop),
// XOR-swizzled LDS (both-sides), setprio around MFMA, XCD-chunked tiles.
__device__ __forceinline__ void store_out(float* p, float v) { *p = v; }
__device__ __forceinline__ void store_out(bf16* p, float v) { *p = __float2bfloat16(v); }

template <typename OutT>
__global__ __launch_bounds__(512, 1) void gemm_nt256(const bf16* __restrict__ A,
                                                     const bf16* __restrict__ B,
                                                     OutT* __restrict__ C,
                                                     int M, int N, int K) {
    __shared__ char lds[131072];  // [buf][A 32KB | B 32KB]
    const int t = threadIdx.x, lane = t & 63, w = t >> 6;
    const int wm = w >> 2, wn = w & 3;
    const int li = lane & 15, hi = lane >> 4, l7 = lane & 7, l3 = lane >> 3;

    // column-major tiles + bijective chunked XCD swizzle: each XCD owns one
    // 256-wide B panel (1MB, L2-resident), A streamed from L3.
    const int ny = M >> 8;
    const int cpx = gridDim.x >> 3;
    const int tile = ((int)blockIdx.x & 7) * cpx + ((int)blockIdx.x >> 3);
    const int m0 = (tile % ny) * 256, n0 = (tile / ny) * 256;
    const int NT = K >> 6;

    f32x4_t acc[8][4];
#pragma unroll
    for (int f = 0; f < 8; ++f)
#pragma unroll
        for (int g = 0; g < 4; ++g) acc[f][g] = f32x4_t{0.f, 0.f, 0.f, 0.f};

    bf16x8_t af[2][8], bfr[2][4];

    // stage tile kt -> buffer p (8 gload_lds per wave: 4 A-chunks + 4 B-chunks,
    // each 8 rows x 128B, source col pre-swizzled so linear LDS == swizzled)
    auto stage = [&](int kt, int p) {
        const char* Ab = (const char*)A;
        const char* Bb = (const char*)B;
        char* la = lds + p * 65536;
        char* lb = la + 32768;
        const int sc = (l7 ^ l3) << 4;
        const size_t kof = (size_t)kt * 128;
#pragma unroll
        for (int c = 0; c < 4; ++c) {
            int row = w * 32 + c * 8 + l3;
            gload_lds16(Ab + (size_t)(m0 + row) * K * 2 + kof + sc,
                        la + (w * 32 + c * 8) * 128);
        }
#pragma unroll
        for (int c = 0; c < 4; ++c) {
            int row = w * 32 + c * 8 + l3;
            gload_lds16(Bb + (size_t)(n0 + row) * K * 2 + kof + sc,
                        lb + (w * 32 + c * 8) * 128);
        }
    };

    auto read_frags = [&](int p) {
        const char* la = lds + p * 65536;
        const char* lb = la + 32768;
#pragma unroll
        for (int kk = 0; kk < 2; ++kk) {
            const int cb = kk * 64 + hi * 16;
#pragma unroll
            for (int f = 0; f < 8; ++f) {
                int r = wm * 128 + f * 16 + li;
                af[kk][f] = *reinterpret_cast<const bf16x8_t*>(
                    la + r * 128 + (cb ^ (l7 << 4)));
            }
#pragma unroll
            for (int g = 0; g < 4; ++g) {
                int r = wn * 64 + g * 16 + li;
                bfr[kk][g] = *reinterpret_cast<const bf16x8_t*>(
                    lb + r * 128 + (cb ^ (l7 << 4)));
            }
        }
    };

    auto do_mfma = [&]() {
        __builtin_amdgcn_s_setprio(1);
#pragma unroll
        for (int kk = 0; kk < 2; ++kk)
#pragma unroll
            for (int f = 0; f < 8; ++f)
#pragma unroll
                for (int g = 0; g < 4; ++g)
                    acc[f][g] = mfma16(af[kk][f], bfr[kk][g], acc[f][g]);
        __builtin_amdgcn_s_setprio(0);
    };

    // prologue: tiles 0,1 in flight; wait tile0 (8 newest = tile1 stay in flight)
    stage(0, 0);
    stage(1, 1);
    asm volatile("s_waitcnt vmcnt(8)" ::: "memory"); SCHED0;
    __builtin_amdgcn_s_barrier(); SCHED0;

    // main loop invariant at top of iter kt: buf[kt&1] resident (all waves),
    // 8 loads of tile kt+1 in flight.
    for (int kt = 0; kt < NT - 2; ++kt) {
        const int p = kt & 1;
        read_frags(p);
        asm volatile("s_waitcnt lgkmcnt(0)" ::: "memory"); SCHED0;
        __builtin_amdgcn_s_barrier(); SCHED0;   // all waves done reading buf[p]
        stage(kt + 2, p);                        // overwrite buf[p] with kt+2
        do_mfma();
        asm volatile("s_waitcnt vmcnt(8)" ::: "memory"); SCHED0;  // kt+1 landed
        __builtin_amdgcn_s_barrier(); SCHED0;
    }
    // kt = NT-2: no stage; drain so NT-1 is resident
    read_frags((NT - 2) & 1);
    asm volatile("s_waitcnt lgkmcnt(0)" ::: "memory"); SCHED0;
    do_mfma();
    asm volatile("s_waitcnt vmcnt(0)" ::: "memory"); SCHED0;
    __builtin_amdgcn_s_barrier(); SCHED0;
    // kt = NT-1
    read_frags((NT - 1) & 1);
    asm volatile("s_waitcnt lgkmcnt(0)" ::: "memory"); SCHED0;
    do_mfma();

    // epilogue
#pragma unroll
    for (int f = 0; f < 8; ++f)
#pragma unroll
        for (int g = 0; g < 4; ++g)
#pragma unroll
            for (int r = 0; r < 4; ++r) {
                int row = m0 + wm * 128 + f * 16 + hi * 4 + r;
                int col = n0 + wn * 64 + g * 16 + li;
                store_out(C + (size_t)row * N + col, acc[f][g][r]);
            }
}

// ---------------------------------------------------------------- RoPE (+scale on q)
// q pre-scale folds 1/sqrt(128) AND log2(e): softmax later runs in base-2.
__global__ __launch_bounds__(256) void rope_qk(bf16* __restrict__ q, bf16* __restrict__ k,
                                               int total) {
    int idx = blockIdx.x * blockDim.x + threadIdx.x;
    if (idx >= total) return;
    int d = idx & 63;
    int h = (idx >> 6) & 15;
    int bt = idx >> 10;            // b*T + t
    int tpos = bt & 2047;
    float freq = expf(-0.14391157f * (float)d);   // ln(10000)/64
    float ang = (float)tpos * freq;
    float s, c;
    sincosf(ang, &s, &c);
    size_t base = (size_t)bt * 2048 + h * 128 + d;
    const float scale_q = 0.12751682f;            // (1/sqrt(128)) * log2(e)
    {
        float x1 = __bfloat162float(q[base]);
        float x2 = __bfloat162float(q[base + 64]);
        q[base]      = __float2bfloat16((x1 * c - x2 * s) * scale_q);
        q[base + 64] = __float2bfloat16((x1 * s + x2 * c) * scale_q);
    }
    {
        float x1 = __bfloat162float(k[base]);
        float x2 = __bfloat162float(k[base + 64]);
        k[base]      = __float2bfloat16(x1 * c - x2 * s);
        k[base + 64] = __float2bfloat16(x1 * s + x2 * c);
    }
}

// ---------------------------------------------------------------- V transpose
// v: [B*T][C] -> vT: [B*H][D][T]
__global__ __launch_bounds__(256) void transpose_v(const bf16* __restrict__ v,
                                                   bf16* __restrict__ vT) {
    __shared__ bf16 tile[64][65];
    const int T = 2048, Cc = 2048;
    int bh = blockIdx.z, b = bh >> 4, h = bh & 15;
    int t0 = blockIdx.x * 64, d0 = blockIdx.y * 64;
    int tx = threadIdx.x & 63, ty = threadIdx.x >> 6;
#pragma unroll
    for (int i = 0; i < 16; i++) {
        int tt = ty + i * 4;
        tile[tt][tx] = v[(size_t)(b * T + t0 + tt) * Cc + h * 128 + d0 + tx];
    }
    __syncthreads();
#pragma unroll
    for (int i = 0; i < 16; i++) {
        int dd = ty + i * 4;
        vT[(size_t)(bh * 128 + d0 + dd) * T + t0 + tx] = tile[tx][dd];
    }
}

// ---------------------------------------------------------------- flash attention
// q,k: [B*T][C] bf16 (rope'd; q pre-scaled incl. log2e -> base-2 softmax).
// vT: [B*H][D][T]. att out: [B*T][C] bf16. grid: (16 pairs, B*H); each block
// does q-blocks {pair, 31-pair} = 33 KV-tiles -> perfect balance.
__global__ __launch_bounds__(256) void flash_attn(const bf16* __restrict__ q,
                                                  const bf16* __restrict__ k,
                                                  const bf16* __restrict__ vT,
                                                  bf16* __restrict__ att) {
    const int T = 2048, Cc = 2048;
    __shared__ bf16 Ks[64 * 128];    // [kv row][d], 256B rows, swizzled
    __shared__ bf16 VTs[128 * 64];   // [d][kv row], 128B rows, swizzled
    __shared__ bf16 Ps[4][16 * 72];  // per-wave P tile, stride 72 elems (144B)
    const int t = threadIdx.x, lane = t & 63, w = t >> 6;
    const int bh = blockIdx.y, b = bh >> 4, h = bh & 15;
    const int col = lane & 15, hi = lane >> 4;

    for (int pass = 0; pass < 2; ++pass) {
        const int qblk = pass ? (31 - (int)blockIdx.x) : (int)blockIdx.x;
        const int q0 = qblk * 64;

        bf16x8_t qf[4];
        {
            int qrow = q0 + w * 16 + col;
            const char* qb = (const char*)q + ((size_t)(b * T + qrow) * Cc + h * 128) * 2;
#pragma unroll
            for (int kf = 0; kf < 4; kf++)
                qf[kf] = *reinterpret_cast<const bf16x8_t*>(qb + kf * 64 + hi * 16);
        }

        f32x4_t acc[8];
#pragma unroll
        for (int i = 0; i < 8; i++) acc[i] = f32x4_t{0.f, 0.f, 0.f, 0.f};
        float m_run[4] = {-1e30f, -1e30f, -1e30f, -1e30f};
        float l_run[4] = {0.f, 0.f, 0.f, 0.f};

        const int ntiles = qblk + 1;  // causal
        for (int ti = 0; ti < ntiles; ++ti) {
            const int k0 = ti * 64;
#pragma unroll
            for (int i = 0; i < 4; ++i) {
                int o = (i * 256 + t) * 16;
                int kr = o >> 8, kc = (o & 255) ^ ((kr & 7) << 4);
                gload_lds16((const char*)k + ((size_t)(b * T + k0 + kr) * Cc + h * 128) * 2 + kc,
                            (char*)Ks + (i * 256 + w * 64) * 16);
                int vr = o >> 7, vc = (o & 127) ^ ((vr & 7) << 4);
                gload_lds16((const char*)vT + ((size_t)(bh * 128 + vr) * T + k0) * 2 + vc,
                            (char*)VTs + (i * 256 + w * 64) * 16);
            }
            __syncthreads();

            // S = q @ k^T  (16 rows x 64 cols per wave), base-2 domain
            f32x4_t s[4];
#pragma unroll
            for (int nb = 0; nb < 4; nb++) {
                s[nb] = f32x4_t{0.f, 0.f, 0.f, 0.f};
#pragma unroll
                for (int kf = 0; kf < 4; kf++) {
                    bf16x8_t kfr = *reinterpret_cast<const bf16x8_t*>(
                        (const char*)Ks + (((nb * 16 + col) * 256 + kf * 64 + hi * 16)
                                           ^ ((col & 7) << 4)));
                    s[nb] = mfma16(qf[kf], kfr, s[nb]);
                }
            }

            // causal mask + online softmax (base 2)
            const int rowb = q0 + w * 16 + (hi << 2);
            float mt[4] = {-1e30f, -1e30f, -1e30f, -1e30f};
#pragma unroll
            for (int nb = 0; nb < 4; nb++) {
                int kc = k0 + nb * 16 + col;
#pragma unroll
                for (int r = 0; r < 4; r++) {
                    float v = s[nb][r];
                    if (kc > rowb + r) v = -1e30f;
                    s[nb][r] = v;
                    mt[r] = fmaxf(mt[r], v);
                }
            }
#pragma unroll
            for (int r = 0; r < 4; r++) {
#pragma unroll
                for (int mk = 1; mk < 16; mk <<= 1)
                    mt[r] = fmaxf(mt[r], __shfl_xor(mt[r], mk, 64));
            }
            float alpha[4], ls[4];
#pragma unroll
            for (int r = 0; r < 4; r++) {
                float mn = fmaxf(m_run[r], mt[r]);
                alpha[r] = exp2f(m_run[r] - mn);
                m_run[r] = mn;
                ls[r] = 0.f;
            }
#pragma unroll
            for (int nb = 0; nb < 4; nb++)
#pragma unroll
                for (int r = 0; r < 4; r++) {
                    float p = exp2f(s[nb][r] - m_run[r]);
                    s[nb][r] = p;
                    ls[r] += p;
                }
#pragma unroll
            for (int r = 0; r < 4; r++) {
#pragma unroll
                for (int mk = 1; mk < 16; mk <<= 1)
                    ls[r] += __shfl_xor(ls[r], mk, 64);
                l_run[r] = l_run[r] * alpha[r] + ls[r];
            }
#pragma unroll
            for (int i = 0; i < 8; i++)
#pragma unroll
                for (int r = 0; r < 4; r++) acc[i][r] *= alpha[r];

            // P (C/D layout) -> LDS (stride 72) -> A-operand layout
#pragma unroll
            for (int nb = 0; nb < 4; nb++)
#pragma unroll
                for (int r = 0; r < 4; r++)
                    Ps[w][((hi << 2) + r) * 72 + nb * 16 + col] =
                        __float2bfloat16(s[nb][r]);
            asm volatile("s_waitcnt lgkmcnt(0)" ::: "memory");
            __builtin_amdgcn_sched_barrier(0);
            bf16x8_t pf[2];
#pragma unroll
            for (int kb = 0; kb < 2; kb++)
                pf[kb] = *reinterpret_cast<const bf16x8_t*>(
                    (const char*)Ps[w] + col * 144 + kb * 64 + hi * 16);

            // O += P @ V
#pragma unroll
            for (int db = 0; db < 8; db++)
#pragma unroll
                for (int kb = 0; kb < 2; kb++) {
                    bf16x8_t vf = *reinterpret_cast<const bf16x8_t*>(
                        (const char*)VTs + (((db * 16 + col) * 128 + kb * 64 + hi * 16)
                                            ^ ((col & 7) << 4)));
                    acc[db] = mfma16(pf[kb], vf, acc[db]);
                }
            __syncthreads();
        }

        // epilogue: normalize + write
#pragma unroll
        for (int r = 0; r < 4; r++) {
            float inv = 1.0f / l_run[r];
            int row = q0 + w * 16 + (hi << 2) + r;
            size_t base = (size_t)(b * T + row) * Cc + h * 128;
#pragma unroll
            for (int db = 0; db < 8; db++)
                att[base + db * 16 + col] = __float2bfloat16(acc[db][r] * inv);
        }
    }
}

// ---------------------------------------------------------------- launcher
extern "C" void kernel_launch(void* const* d_in, const int* in_sizes, int n_in,
                              void* d_out, int out_size, void* d_ws, size_t ws_size,
                              hipStream_t stream) {
    const int B = 4, T = 2048, C = 2048;
    const int M = B * T;  // 8192
    const float* x  = (const float*)d_in[0];
    const float* wq = (const float*)d_in[1];
    const float* wk = (const float*)d_in[2];
    const float* wv = (const float*)d_in[3];
    const float* wo = (const float*)d_in[4];
    float* out = (float*)d_out;

    char* ws = (char*)d_ws;
    const size_t SZ_X = (size_t)M * C * 2;       // 33554432
    const size_t SZ_W = (size_t)C * C * 2;       // 8388608
    bf16* xb   = (bf16*)(ws);
    bf16* wqb  = (bf16*)(ws + SZ_X);
    bf16* wkb  = (bf16*)(ws + SZ_X + SZ_W);
    bf16* wvb  = (bf16*)(ws + SZ_X + 2 * SZ_W);
    bf16* wob  = (bf16*)(ws + SZ_X + 3 * SZ_W);
    bf16* qb   = (bf16*)(ws + SZ_X + 4 * SZ_W);
    bf16* kb   = (bf16*)(ws + 2 * SZ_X + 4 * SZ_W);
    bf16* vb   = (bf16*)(ws + 3 * SZ_X + 4 * SZ_W);
    bf16* vTb  = (bf16*)(ws + 4 * SZ_X + 4 * SZ_W);
    bf16* attb = (bf16*)(ws + 5 * SZ_X + 4 * SZ_W);

    // 1) casts
    cast_f32_bf16<<<2048, 256, 0, stream>>>(x, xb, M * C / 4);
    cast_f32_bf16<<<1024, 256, 0, stream>>>(wq, wqb, C * C / 4);
    cast_f32_bf16<<<1024, 256, 0, stream>>>(wk, wkb, C * C / 4);
    cast_f32_bf16<<<1024, 256, 0, stream>>>(wv, wvb, C * C / 4);
    cast_f32_bf16<<<1024, 256, 0, stream>>>(wo, wob, C * C / 4);

    // 2) QKV projections (256 blocks = (8192/256)*(2048/256), one per CU)
    const int nblk = (M / 256) * (C / 256);
    gemm_nt256<bf16><<<nblk, 512, 0, stream>>>(xb, wqb, qb, M, C, C);
    gemm_nt256<bf16><<<nblk, 512, 0, stream>>>(xb, wkb, kb, M, C, C);
    gemm_nt256<bf16><<<nblk, 512, 0, stream>>>(xb, wvb, vb, M, C, C);

    // 3) RoPE + scale (q gets 1/sqrt(d) * log2e)
    int rope_total = B * T * 16 * 64;
    rope_qk<<<rope_total / 256, 256, 0, stream>>>(qb, kb, rope_total);

    // 4) V transpose
    transpose_v<<<dim3(T / 64, 2, B * 16), 256, 0, stream>>>(vb, vTb);

    // 5) flash attention (paired q-blocks: uniform 33 tiles/block)
    flash_attn<<<dim3(16, B * 16), 256, 0, stream>>>(qb, kb, vTb, attb);

    // 6) output projection (fp32 out)
    gemm_nt256<float><<<nblk, 512, 0, stream>>>(attb, wob, out, M, C, C);
}

// Round 5
// 712.624 us; speedup vs baseline: 1.6194x; 1.1229x over previous
//
#include <hip/hip_runtime.h>
#include <hip/hip_bf16.h>
#include <stdint.h>

typedef __hip_bfloat16 bf16;
typedef __bf16 bf16x8_t __attribute__((ext_vector_type(8)));
typedef float f32x4_t __attribute__((ext_vector_type(4)));

#define GAS __attribute__((address_space(1)))
#define LAS __attribute__((address_space(3)))
#define SCHED0 __builtin_amdgcn_sched_barrier(0)

__device__ __forceinline__ f32x4_t mfma16(bf16x8_t a, bf16x8_t b, f32x4_t c) {
    return __builtin_amdgcn_mfma_f32_16x16x32_bf16(a, b, c, 0, 0, 0);
}

// global -> LDS async copy, 16B per lane. LDS dest wave-uniform base + lane*16;
// global source IS per-lane (swizzle there).
__device__ __forceinline__ void gload_lds16(const void* g, void* l) {
    __builtin_amdgcn_global_load_lds((const GAS void*)g, (LAS void*)l, 16, 0, 0);
}

// native 2^x (exp2f w/o fast-math doesn't lower to v_exp_f32).
// s_nop covers the VALU-trans result hazard for inline asm.
__device__ __forceinline__ float exp2_fast(float x) {
    float r;
    asm volatile("v_exp_f32 %0, %1\n\ts_nop 0" : "=v"(r) : "v"(x));
    return r;
}

// ---------------------------------------------------------------- cast fp32->bf16
__global__ __launch_bounds__(256) void cast_f32_bf16(const float* __restrict__ in,
                                                     bf16* __restrict__ out, int n4) {
    int stride = gridDim.x * blockDim.x;
    for (int i = blockIdx.x * blockDim.x + threadIdx.x; i < n4; i += stride) {
        float4 f = reinterpret_cast<const float4*>(in)[i];
        bf16 h0 = __float2bfloat16(f.x), h1 = __float2bfloat16(f.y);
        bf16 h2 = __float2bfloat16(f.z), h3 = __float2bfloat16(f.w);
        ushort4 u;
        u.x = *reinterpret_cast<unsigned short*>(&h0);
        u.y = *reinterpret_cast<unsigned short*>(&h1);
        u.z = *reinterpret_cast<unsigned short*>(&h2);
        u.w = *reinterpret_cast<unsigned short*>(&h3);
        reinterpret_cast<ushort4*>(out)[i] = u;
    }
}

// ---------------------------------------------------------------- NT GEMM 256x256
// 8-phase schedule (T3+T4): per iteration = 2 K-tiles (BK=64 each), 8 phases of
// {ds_read subtile | stage 1 half-tile | barrier | lgkm0 | 16 MFMA | barrier},
// vmcnt(4) only at phases 4,8 (2 half-tiles in flight, never drained).
// 256x256 tile, 512 thr (8 waves 2Mx4N), 128KiB dbuf LDS, both-sides XOR swizzle.
__device__ __forceinline__ void store_out(float* p, float v) { *p = v; }
__device__ __forceinline__ void store_out(bf16* p, float v) { *p = __float2bfloat16(v); }

#define BAR()   do { SCHED0; __builtin_amdgcn_s_barrier(); SCHED0; } while (0)
#define LGKM0() do { asm volatile("s_waitcnt lgkmcnt(0)" ::: "memory"); SCHED0; } while (0)
#define VM4()   do { asm volatile("s_waitcnt vmcnt(4)" ::: "memory"); SCHED0; } while (0)

// 8 ds_read_b128: af[kk][MLO..MLO+3] from buffer P
#define READ_A(P, MLO)                                                          \
    do {                                                                        \
        const char* la_ = lds + (P) * 65536;                                    \
        _Pragma("unroll") for (int kk = 0; kk < 2; ++kk)                        \
        _Pragma("unroll") for (int f = 0; f < 4; ++f) {                         \
            int r_ = wm * 128 + ((MLO) + f) * 16 + li;                          \
            af[kk][(MLO) + f] = *reinterpret_cast<const bf16x8_t*>(             \
                la_ + r_ * 128 + ((kk * 64 + hi * 16) ^ (l7 << 4)));            \
        }                                                                       \
    } while (0)

// 4 ds_read_b128: bfr[kk][NLO..NLO+1] from buffer P
#define READ_B(P, NLO)                                                          \
    do {                                                                        \
        const char* lb_ = lds + (P) * 65536 + 32768;                            \
        _Pragma("unroll") for (int kk = 0; kk < 2; ++kk)                        \
        _Pragma("unroll") for (int g = 0; g < 2; ++g) {                         \
            int r_ = wn * 64 + ((NLO) + g) * 16 + li;                           \
            bfr[kk][(NLO) + g] = *reinterpret_cast<const bf16x8_t*>(            \
                lb_ + r_ * 128 + ((kk * 64 + hi * 16) ^ (l7 << 4)));            \
        }                                                                       \
    } while (0)

// 16 MFMA: one C quadrant (4m x 2n) x BK=64
#define MFMA_Q(MLO, NLO)                                                        \
    do {                                                                        \
        __builtin_amdgcn_s_setprio(1);                                          \
        _Pragma("unroll") for (int kk = 0; kk < 2; ++kk)                        \
        _Pragma("unroll") for (int f = 0; f < 4; ++f)                           \
        _Pragma("unroll") for (int g = 0; g < 2; ++g)                           \
            acc[(MLO) + f][(NLO) + g] = mfma16(af[kk][(MLO) + f],               \
                                               bfr[kk][(NLO) + g],              \
                                               acc[(MLO) + f][(NLO) + g]);      \
        __builtin_amdgcn_s_setprio(0);                                          \
    } while (0)

template <typename OutT>
__global__ __launch_bounds__(512, 2) void gemm_nt256(const bf16* __restrict__ A,
                                                     const bf16* __restrict__ B,
                                                     OutT* __restrict__ C,
                                                     int M, int N, int K) {
    __shared__ char lds[131072];  // [buf][A 32KB | B 32KB]
    const int t = threadIdx.x, lane = t & 63, w = t >> 6;
    const int wm = w >> 2, wn = w & 3;
    const int li = lane & 15, hi = lane >> 4, l7 = lane & 7, l3 = lane >> 3;

    // column-major tiles + chunked XCD swizzle: each XCD owns one 256-col B panel.
    const int ny = M >> 8;
    const int cpx = gridDim.x >> 3;
    const int tile = ((int)blockIdx.x & 7) * cpx + ((int)blockIdx.x >> 3);
    const int m0 = (tile % ny) * 256, n0 = (tile / ny) * 256;
    const int NT = K >> 6;

    f32x4_t acc[8][4];
#pragma unroll
    for (int f = 0; f < 8; ++f)
#pragma unroll
        for (int g = 0; g < 4; ++g) acc[f][g] = f32x4_t{0.f, 0.f, 0.f, 0.f};

    bf16x8_t af[2][8], bfr[2][4];

    // stage one half-tile (2 gload_lds/thread): half 0=A rows 0-127, 1=A rows
    // 128-255, 2=B rows 0-127, 3=B rows 128-255. kt clamped (not skipped) so
    // the vmcnt load-count arithmetic stays exact in the last iteration.
    auto stage_half = [&](int kt, int half, int p) {
        kt = kt < NT - 1 ? kt : NT - 1;
        const bf16* src = (half >= 2) ? B : A;
        const int rb = ((half >= 2) ? n0 : m0) + (half & 1) * 128;
        char* dst = lds + p * 65536 + (half >= 2 ? 32768 : 0) + (half & 1) * 16384;
        const int sc = (l7 ^ l3) << 4;
#pragma unroll
        for (int l = 0; l < 2; ++l) {
            int row = rb + l * 64 + w * 8 + l3;
            gload_lds16((const char*)src + (size_t)row * K * 2 + (size_t)kt * 128 + sc,
                        dst + (l * 64 + w * 8) * 128);
        }
    };

    // prologue: tile0 fully staged + tile1 A halves; tile0 landed, 2 halves fly.
    stage_half(0, 0, 0); stage_half(0, 1, 0); stage_half(0, 2, 0); stage_half(0, 3, 0);
    stage_half(1, 0, 1); stage_half(1, 1, 1);
    VM4(); BAR();

    const int NITER = NT >> 1;
    for (int j = 0; j < NITER; ++j) {
        const int t1 = 2 * j + 1;
        // ---- K-tile 2j (buf0) ----
        // P1
        READ_A(0, 0); READ_B(0, 0); stage_half(t1, 2, 1);
        BAR(); LGKM0(); MFMA_Q(0, 0); BAR();
        // P2
        READ_A(0, 4); READ_B(0, 2); stage_half(t1, 3, 1);
        BAR(); LGKM0(); MFMA_Q(0, 2); BAR();
        // P3 (buf0 free: stage next-even tile)
        stage_half(t1 + 1, 0, 0);
        BAR(); MFMA_Q(4, 0); BAR();
        // P4
        stage_half(t1 + 1, 1, 0);
        BAR(); MFMA_Q(4, 2); VM4(); BAR();   // tile 2j+1 fully landed
        // ---- K-tile 2j+1 (buf1) ----
        // P5
        READ_A(1, 0); READ_B(1, 0); stage_half(t1 + 1, 2, 0);
        BAR(); LGKM0(); MFMA_Q(0, 0); BAR();
        // P6
        READ_A(1, 4); READ_B(1, 2); stage_half(t1 + 1, 3, 0);
        BAR(); LGKM0(); MFMA_Q(0, 2); BAR();
        // P7 (buf1 free: stage next-odd tile)
        stage_half(t1 + 2, 0, 1);
        BAR(); MFMA_Q(4, 0); BAR();
        // P8
        stage_half(t1 + 2, 1, 1);
        BAR(); MFMA_Q(4, 2); VM4(); BAR();   // tile 2j+2 fully landed
    }

    // epilogue
#pragma unroll
    for (int f = 0; f < 8; ++f)
#pragma unroll
        for (int g = 0; g < 4; ++g)
#pragma unroll
            for (int r = 0; r < 4; ++r) {
                int row = m0 + wm * 128 + f * 16 + hi * 4 + r;
                int col = n0 + wn * 64 + g * 16 + li;
                store_out(C + (size_t)row * N + col, acc[f][g][r]);
            }
}

// ---------------------------------------------------------------- RoPE (+scale on q)
// q pre-scale folds 1/sqrt(128) AND log2(e): softmax later runs in base-2.
__global__ __launch_bounds__(256) void rope_qk(bf16* __restrict__ q, bf16* __restrict__ k,
                                               int total) {
    int idx = blockIdx.x * blockDim.x + threadIdx.x;
    if (idx >= total) return;
    int d = idx & 63;
    int h = (idx >> 6) & 15;
    int bt = idx >> 10;            // b*T + t
    int tpos = bt & 2047;
    float freq = expf(-0.14391157f * (float)d);   // ln(10000)/64
    float ang = (float)tpos * freq;
    float s, c;
    sincosf(ang, &s, &c);
    size_t base = (size_t)bt * 2048 + h * 128 + d;
    const float scale_q = 0.12751682f;            // (1/sqrt(128)) * log2(e)
    {
        float x1 = __bfloat162float(q[base]);
        float x2 = __bfloat162float(q[base + 64]);
        q[base]      = __float2bfloat16((x1 * c - x2 * s) * scale_q);
        q[base + 64] = __float2bfloat16((x1 * s + x2 * c) * scale_q);
    }
    {
        float x1 = __bfloat162float(k[base]);
        float x2 = __bfloat162float(k[base + 64]);
        k[base]      = __float2bfloat16(x1 * c - x2 * s);
        k[base + 64] = __float2bfloat16(x1 * s + x2 * c);
    }
}

// ---------------------------------------------------------------- V transpose
// v: [B*T][C] -> vT: [B*H][D][T]
__global__ __launch_bounds__(256) void transpose_v(const bf16* __restrict__ v,
                                                   bf16* __restrict__ vT) {
    __shared__ bf16 tile[64][65];
    const int T = 2048, Cc = 2048;
    int bh = blockIdx.z, b = bh >> 4, h = bh & 15;
    int t0 = blockIdx.x * 64, d0 = blockIdx.y * 64;
    int tx = threadIdx.x & 63, ty = threadIdx.x >> 6;
#pragma unroll
    for (int i = 0; i < 16; i++) {
        int tt = ty + i * 4;
        tile[tt][tx] = v[(size_t)(b * T + t0 + tt) * Cc + h * 128 + d0 + tx];
    }
    __syncthreads();
#pragma unroll
    for (int i = 0; i < 16; i++) {
        int dd = ty + i * 4;
        vT[(size_t)(bh * 128 + d0 + dd) * T + t0 + tx] = tile[tx][dd];
    }
}

// ---------------------------------------------------------------- flash attention
// q,k: [B*T][C] bf16 (rope'd; q pre-scaled incl. log2e -> base-2 softmax).
// vT: [B*H][D][T]. att out: [B*T][C] bf16. grid: (16 pairs, B*H); each block
// does q-blocks {pair, 31-pair} = 33 KV-tiles -> perfect balance.
__global__ __launch_bounds__(256) void flash_attn(const bf16* __restrict__ q,
                                                  const bf16* __restrict__ k,
                                                  const bf16* __restrict__ vT,
                                                  bf16* __restrict__ att) {
    const int T = 2048, Cc = 2048;
    __shared__ bf16 Ks[64 * 128];    // [kv row][d], 256B rows, swizzled
    __shared__ bf16 VTs[128 * 64];   // [d][kv row], 128B rows, swizzled
    __shared__ bf16 Ps[4][16 * 72];  // per-wave P tile, stride 72 elems (144B)
    const int t = threadIdx.x, lane = t & 63, w = t >> 6;
    const int bh = blockIdx.y, b = bh >> 4, h = bh & 15;
    const int col = lane & 15, hi = lane >> 4;

    for (int pass = 0; pass < 2; ++pass) {
        const int qblk = pass ? (31 - (int)blockIdx.x) : (int)blockIdx.x;
        const int q0 = qblk * 64;

        bf16x8_t qf[4];
        {
            int qrow = q0 + w * 16 + col;
            const char* qb = (const char*)q + ((size_t)(b * T + qrow) * Cc + h * 128) * 2;
#pragma unroll
            for (int kf = 0; kf < 4; kf++)
                qf[kf] = *reinterpret_cast<const bf16x8_t*>(qb + kf * 64 + hi * 16);
        }

        f32x4_t acc[8];
#pragma unroll
        for (int i = 0; i < 8; i++) acc[i] = f32x4_t{0.f, 0.f, 0.f, 0.f};
        float m_run[4] = {-1e30f, -1e30f, -1e30f, -1e30f};
        float l_run[4] = {0.f, 0.f, 0.f, 0.f};

        const int ntiles = qblk + 1;  // causal
        for (int ti = 0; ti < ntiles; ++ti) {
            const int k0 = ti * 64;
#pragma unroll
            for (int i = 0; i < 4; ++i) {
                int o = (i * 256 + t) * 16;
                int kr = o >> 8, kc = (o & 255) ^ ((kr & 7) << 4);
                gload_lds16((const char*)k + ((size_t)(b * T + k0 + kr) * Cc + h * 128) * 2 + kc,
                            (char*)Ks + (i * 256 + w * 64) * 16);
                int vr = o >> 7, vc = (o & 127) ^ ((vr & 7) << 4);
                gload_lds16((const char*)vT + ((size_t)(bh * 128 + vr) * T + k0) * 2 + vc,
                            (char*)VTs + (i * 256 + w * 64) * 16);
            }
            __syncthreads();

            // S = q @ k^T  (16 rows x 64 cols per wave), base-2 domain
            f32x4_t s[4];
#pragma unroll
            for (int nb = 0; nb < 4; nb++) {
                s[nb] = f32x4_t{0.f, 0.f, 0.f, 0.f};
#pragma unroll
                for (int kf = 0; kf < 4; kf++) {
                    bf16x8_t kfr = *reinterpret_cast<const bf16x8_t*>(
                        (const char*)Ks + (((nb * 16 + col) * 256 + kf * 64 + hi * 16)
                                           ^ ((col & 7) << 4)));
                    s[nb] = mfma16(qf[kf], kfr, s[nb]);
                }
            }

            // causal mask + online softmax (base 2)
            const int rowb = q0 + w * 16 + (hi << 2);
            float mt[4] = {-1e30f, -1e30f, -1e30f, -1e30f};
#pragma unroll
            for (int nb = 0; nb < 4; nb++) {
                int kc = k0 + nb * 16 + col;
#pragma unroll
                for (int r = 0; r < 4; r++) {
                    float v = s[nb][r];
                    if (kc > rowb + r) v = -1e30f;
                    s[nb][r] = v;
                    mt[r] = fmaxf(mt[r], v);
                }
            }
#pragma unroll
            for (int r = 0; r < 4; r++) {
#pragma unroll
                for (int mk = 1; mk < 16; mk <<= 1)
                    mt[r] = fmaxf(mt[r], __shfl_xor(mt[r], mk, 64));
            }
            float alpha[4], ls[4];
#pragma unroll
            for (int r = 0; r < 4; r++) {
                float mn = fmaxf(m_run[r], mt[r]);
                alpha[r] = exp2_fast(m_run[r] - mn);
                m_run[r] = mn;
                ls[r] = 0.f;
            }
#pragma unroll
            for (int nb = 0; nb < 4; nb++)
#pragma unroll
                for (int r = 0; r < 4; r++) {
                    float p = exp2_fast(s[nb][r] - m_run[r]);
                    s[nb][r] = p;
                    ls[r] += p;
                }
#pragma unroll
            for (int r = 0; r < 4; r++) {
#pragma unroll
                for (int mk = 1; mk < 16; mk <<= 1)
                    ls[r] += __shfl_xor(ls[r], mk, 64);
                l_run[r] = l_run[r] * alpha[r] + ls[r];
            }
#pragma unroll
            for (int i = 0; i < 8; i++)
#pragma unroll
                for (int r = 0; r < 4; r++) acc[i][r] *= alpha[r];

            // P (C/D layout) -> LDS (stride 72) -> A-operand layout
#pragma unroll
            for (int nb = 0; nb < 4; nb++)
#pragma unroll
                for (int r = 0; r < 4; r++)
                    Ps[w][((hi << 2) + r) * 72 + nb * 16 + col] =
                        __float2bfloat16(s[nb][r]);
            asm volatile("s_waitcnt lgkmcnt(0)" ::: "memory");
            __builtin_amdgcn_sched_barrier(0);
            bf16x8_t pf[2];
#pragma unroll
            for (int kb = 0; kb < 2; kb++)
                pf[kb] = *reinterpret_cast<const bf16x8_t*>(
                    (const char*)Ps[w] + col * 144 + kb * 64 + hi * 16);

            // O += P @ V
#pragma unroll
            for (int db = 0; db < 8; db++)
#pragma unroll
                for (int kb = 0; kb < 2; kb++) {
                    bf16x8_t vf = *reinterpret_cast<const bf16x8_t*>(
                        (const char*)VTs + (((db * 16 + col) * 128 + kb * 64 + hi * 16)
                                            ^ ((col & 7) << 4)));
                    acc[db] = mfma16(pf[kb], vf, acc[db]);
                }
            __syncthreads();
        }

        // epilogue: normalize + write
#pragma unroll
        for (int r = 0; r < 4; r++) {
            float inv = 1.0f / l_run[r];
            int row = q0 + w * 16 + (hi << 2) + r;
            size_t base = (size_t)(b * T + row) * Cc + h * 128;
#pragma unroll
            for (int db = 0; db < 8; db++)
                att[base + db * 16 + col] = __float2bfloat16(acc[db][r] * inv);
        }
    }
}

// ---------------------------------------------------------------- launcher
extern "C" void kernel_launch(void* const* d_in, const int* in_sizes, int n_in,
                              void* d_out, int out_size, void* d_ws, size_t ws_size,
                              hipStream_t stream) {
    const int B = 4, T = 2048, C = 2048;
    const int M = B * T;  // 8192
    const float* x  = (const float*)d_in[0];
    const float* wq = (const float*)d_in[1];
    const float* wk = (const float*)d_in[2];
    const float* wv = (const float*)d_in[3];
    const float* wo = (const float*)d_in[4];
    float* out = (float*)d_out;

    char* ws = (char*)d_ws;
    const size_t SZ_X = (size_t)M * C * 2;       // 33554432
    const size_t SZ_W = (size_t)C * C * 2;       // 8388608
    bf16* xb   = (bf16*)(ws);
    bf16* wqb  = (bf16*)(ws + SZ_X);
    bf16* wkb  = (bf16*)(ws + SZ_X + SZ_W);
    bf16* wvb  = (bf16*)(ws + SZ_X + 2 * SZ_W);
    bf16* wob  = (bf16*)(ws + SZ_X + 3 * SZ_W);
    bf16* qb   = (bf16*)(ws + SZ_X + 4 * SZ_W);
    bf16* kb   = (bf16*)(ws + 2 * SZ_X + 4 * SZ_W);
    bf16* vb   = (bf16*)(ws + 3 * SZ_X + 4 * SZ_W);
    bf16* vTb  = (bf16*)(ws + 4 * SZ_X + 4 * SZ_W);
    bf16* attb = (bf16*)(ws + 5 * SZ_X + 4 * SZ_W);

    // 1) casts
    cast_f32_bf16<<<2048, 256, 0, stream>>>(x, xb, M * C / 4);
    cast_f32_bf16<<<1024, 256, 0, stream>>>(wq, wqb, C * C / 4);
    cast_f32_bf16<<<1024, 256, 0, stream>>>(wk, wkb, C * C / 4);
    cast_f32_bf16<<<1024, 256, 0, stream>>>(wv, wvb, C * C / 4);
    cast_f32_bf16<<<1024, 256, 0, stream>>>(wo, wob, C * C / 4);

    // 2) QKV projections (256 blocks = (8192/256)*(2048/256), one per CU)
    const int nblk = (M / 256) * (C / 256);
    gemm_nt256<bf16><<<nblk, 512, 0, stream>>>(xb, wqb, qb, M, C, C);
    gemm_nt256<bf16><<<nblk, 512, 0, stream>>>(xb, wkb, kb, M, C, C);
    gemm_nt256<bf16><<<nblk, 512, 0, stream>>>(xb, wvb, vb, M, C, C);

    // 3) RoPE + scale (q gets 1/sqrt(d) * log2e)
    int rope_total = B * T * 16 * 64;
    rope_qk<<<rope_total / 256, 256, 0, stream>>>(qb, kb, rope_total);

    // 4) V transpose
    transpose_v<<<dim3(T / 64, 2, B * 16), 256, 0, stream>>>(vb, vTb);

    // 5) flash attention (paired q-blocks: uniform 33 tiles/block)
    flash_attn<<<dim3(16, B * 16), 256, 0, stream>>>(qb, kb, vTb, attb);

    // 6) output projection (fp32 out)
    gemm_nt256<float><<<nblk, 512, 0, stream>>>(attb, wob, out, M, C, C);
}

// Round 7
// 689.360 us; speedup vs baseline: 1.6741x; 1.0337x over previous
//
#include <hip/hip_runtime.h>
#include <hip/hip_bf16.h>
#include <stdint.h>

typedef __hip_bfloat16 bf16;
typedef __bf16 bf16x8_t __attribute__((ext_vector_type(8)));
typedef float f32x4_t __attribute__((ext_vector_type(4)));

#define GAS __attribute__((address_space(1)))
#define LAS __attribute__((address_space(3)))
#define SCHED0 __builtin_amdgcn_sched_barrier(0)

__device__ __forceinline__ f32x4_t mfma16(bf16x8_t a, bf16x8_t b, f32x4_t c) {
    return __builtin_amdgcn_mfma_f32_16x16x32_bf16(a, b, c, 0, 0, 0);
}

// global -> LDS async copy, 16B per lane. LDS dest wave-uniform base + lane*16;
// global source IS per-lane (swizzle there).
__device__ __forceinline__ void gload_lds16(const void* g, void* l) {
    __builtin_amdgcn_global_load_lds((const GAS void*)g, (LAS void*)l, 16, 0, 0);
}

// native transcendentals (libm exp2f/sincosf don't lower to v_exp/v_sin
// without fast-math). s_nop covers the VALU-trans result hazard.
__device__ __forceinline__ float exp2_fast(float x) {
    float r;
    asm volatile("v_exp_f32 %0, %1\n\ts_nop 0" : "=v"(r) : "v"(x));
    return r;
}
__device__ __forceinline__ float sin2pi(float x) {  // x in revolutions [0,1)
    float r;
    asm volatile("v_sin_f32 %0, %1\n\ts_nop 0" : "=v"(r) : "v"(x));
    return r;
}
__device__ __forceinline__ float cos2pi(float x) {
    float r;
    asm volatile("v_cos_f32 %0, %1\n\ts_nop 0" : "=v"(r) : "v"(x));
    return r;
}

// ---------------------------------------------------------------- cast fp32->bf16
__global__ __launch_bounds__(256) void cast_f32_bf16(const float* __restrict__ in,
                                                     bf16* __restrict__ out, int n4) {
    int stride = gridDim.x * blockDim.x;
    for (int i = blockIdx.x * blockDim.x + threadIdx.x; i < n4; i += stride) {
        float4 f = reinterpret_cast<const float4*>(in)[i];
        bf16 h0 = __float2bfloat16(f.x), h1 = __float2bfloat16(f.y);
        bf16 h2 = __float2bfloat16(f.z), h3 = __float2bfloat16(f.w);
        ushort4 u;
        u.x = *reinterpret_cast<unsigned short*>(&h0);
        u.y = *reinterpret_cast<unsigned short*>(&h1);
        u.z = *reinterpret_cast<unsigned short*>(&h2);
        u.w = *reinterpret_cast<unsigned short*>(&h3);
        reinterpret_cast<ushort4*>(out)[i] = u;
    }
}

// all 4 weight matrices in one dispatch; dsts are contiguous in ws.
__global__ __launch_bounds__(256) void cast_w4(const float* __restrict__ w0,
                                               const float* __restrict__ w1,
                                               const float* __restrict__ w2,
                                               const float* __restrict__ w3,
                                               bf16* __restrict__ out) {
    const int n4each = 1 << 20;  // 2048*2048/4
    int stride = gridDim.x * blockDim.x;
    for (int i = blockIdx.x * blockDim.x + threadIdx.x; i < 4 * n4each; i += stride) {
        int li = i & (n4each - 1);
        const float* src = (i < 2 * n4each) ? (i < n4each ? w0 : w1)
                                            : (i < 3 * n4each ? w2 : w3);
        float4 f = reinterpret_cast<const float4*>(src)[li];
        bf16 h0 = __float2bfloat16(f.x), h1 = __float2bfloat16(f.y);
        bf16 h2 = __float2bfloat16(f.z), h3 = __float2bfloat16(f.w);
        ushort4 u;
        u.x = *reinterpret_cast<unsigned short*>(&h0);
        u.y = *reinterpret_cast<unsigned short*>(&h1);
        u.z = *reinterpret_cast<unsigned short*>(&h2);
        u.w = *reinterpret_cast<unsigned short*>(&h3);
        reinterpret_cast<ushort4*>(out)[i] = u;
    }
}

// ---------------------------------------------------------------- NT GEMM 256x256
// 8-phase schedule (T3+T4): per iteration = 2 K-tiles (BK=64 each), 8 phases of
// {ds_read subtile | stage 1 half-tile | barrier | lgkm0 | 16 MFMA | barrier},
// vmcnt(4) only at phases 4,8 (2 half-tiles in flight, never drained).
// 256x256 tile, 512 thr (8 waves 2Mx4N), 128KiB dbuf LDS, both-sides XOR swizzle.
__device__ __forceinline__ void store_out(float* p, float v) { *p = v; }
__device__ __forceinline__ void store_out(bf16* p, float v) { *p = __float2bfloat16(v); }

#define BAR()   do { SCHED0; __builtin_amdgcn_s_barrier(); SCHED0; } while (0)
#define LGKM0() do { asm volatile("s_waitcnt lgkmcnt(0)" ::: "memory"); SCHED0; } while (0)
#define VM4()   do { asm volatile("s_waitcnt vmcnt(4)" ::: "memory"); SCHED0; } while (0)

// 8 ds_read_b128: af[kk][MLO..MLO+3] from buffer P
#define READ_A(P, MLO)                                                          \
    do {                                                                        \
        const char* la_ = lds + (P) * 65536;                                    \
        _Pragma("unroll") for (int kk = 0; kk < 2; ++kk)                        \
        _Pragma("unroll") for (int f = 0; f < 4; ++f) {                         \
            int r_ = wm * 128 + ((MLO) + f) * 16 + li;                          \
            af[kk][(MLO) + f] = *reinterpret_cast<const bf16x8_t*>(             \
                la_ + r_ * 128 + ((kk * 64 + hi * 16) ^ (l7 << 4)));            \
        }                                                                       \
    } while (0)

// 4 ds_read_b128: bfr[kk][NLO..NLO+1] from buffer P
#define READ_B(P, NLO)                                                          \
    do {                                                                        \
        const char* lb_ = lds + (P) * 65536 + 32768;                            \
        _Pragma("unroll") for (int kk = 0; kk < 2; ++kk)                        \
        _Pragma("unroll") for (int g = 0; g < 2; ++g) {                         \
            int r_ = wn * 64 + ((NLO) + g) * 16 + li;                           \
            bfr[kk][(NLO) + g] = *reinterpret_cast<const bf16x8_t*>(            \
                lb_ + r_ * 128 + ((kk * 64 + hi * 16) ^ (l7 << 4)));            \
        }                                                                       \
    } while (0)

// 16 MFMA: one C quadrant (4m x 2n) x BK=64
#define MFMA_Q(MLO, NLO)                                                        \
    do {                                                                        \
        __builtin_amdgcn_s_setprio(1);                                          \
        _Pragma("unroll") for (int kk = 0; kk < 2; ++kk)                        \
        _Pragma("unroll") for (int f = 0; f < 4; ++f)                           \
        _Pragma("unroll") for (int g = 0; g < 2; ++g)                           \
            acc[(MLO) + f][(NLO) + g] = mfma16(af[kk][(MLO) + f],               \
                                               bfr[kk][(NLO) + g],              \
                                               acc[(MLO) + f][(NLO) + g]);      \
        __builtin_amdgcn_s_setprio(0);                                          \
    } while (0)

template <typename OutT>
__global__ __launch_bounds__(512, 2) void gemm_nt256(const bf16* __restrict__ A,
                                                     const bf16* __restrict__ B,
                                                     OutT* __restrict__ C,
                                                     int M, int N, int K) {
    __shared__ char lds[131072];  // [buf][A 32KB | B 32KB]
    const int t = threadIdx.x, lane = t & 63, w = t >> 6;
    const int wm = w >> 2, wn = w & 3;
    const int li = lane & 15, hi = lane >> 4, l7 = lane & 7, l3 = lane >> 3;

    // column-major tiles + chunked XCD swizzle: each XCD owns one 256-col B panel.
    const int ny = M >> 8;
    const int cpx = gridDim.x >> 3;
    const int tile = ((int)blockIdx.x & 7) * cpx + ((int)blockIdx.x >> 3);
    const int m0 = (tile % ny) * 256, n0 = (tile / ny) * 256;
    const int NT = K >> 6;

    f32x4_t acc[8][4];
#pragma unroll
    for (int f = 0; f < 8; ++f)
#pragma unroll
        for (int g = 0; g < 4; ++g) acc[f][g] = f32x4_t{0.f, 0.f, 0.f, 0.f};

    bf16x8_t af[2][8], bfr[2][4];

    // stage one half-tile (2 gload_lds/thread): half 0=A rows 0-127, 1=A rows
    // 128-255, 2=B rows 0-127, 3=B rows 128-255. kt clamped (not skipped) so
    // the vmcnt load-count arithmetic stays exact in the last iteration.
    auto stage_half = [&](int kt, int half, int p) {
        kt = kt < NT - 1 ? kt : NT - 1;
        const bf16* src = (half >= 2) ? B : A;
        const int rb = ((half >= 2) ? n0 : m0) + (half & 1) * 128;
        char* dst = lds + p * 65536 + (half >= 2 ? 32768 : 0) + (half & 1) * 16384;
        const int sc = (l7 ^ l3) << 4;
#pragma unroll
        for (int l = 0; l < 2; ++l) {
            int row = rb + l * 64 + w * 8 + l3;
            gload_lds16((const char*)src + (size_t)row * K * 2 + (size_t)kt * 128 + sc,
                        dst + (l * 64 + w * 8) * 128);
        }
    };

    // prologue: tile0 fully staged + tile1 A halves; tile0 landed, 2 halves fly.
    stage_half(0, 0, 0); stage_half(0, 1, 0); stage_half(0, 2, 0); stage_half(0, 3, 0);
    stage_half(1, 0, 1); stage_half(1, 1, 1);
    VM4(); BAR();

    const int NITER = NT >> 1;
    for (int j = 0; j < NITER; ++j) {
        const int t1 = 2 * j + 1;
        // ---- K-tile 2j (buf0) ----
        // P1
        READ_A(0, 0); READ_B(0, 0); stage_half(t1, 2, 1);
        BAR(); LGKM0(); MFMA_Q(0, 0); BAR();
        // P2
        READ_A(0, 4); READ_B(0, 2); stage_half(t1, 3, 1);
        BAR(); LGKM0(); MFMA_Q(0, 2); BAR();
        // P3 (buf0 free: stage next-even tile)
        stage_half(t1 + 1, 0, 0);
        BAR(); MFMA_Q(4, 0); BAR();
        // P4
        stage_half(t1 + 1, 1, 0);
        BAR(); MFMA_Q(4, 2); VM4(); BAR();   // tile 2j+1 fully landed
        // ---- K-tile 2j+1 (buf1) ----
        // P5
        READ_A(1, 0); READ_B(1, 0); stage_half(t1 + 1, 2, 0);
        BAR(); LGKM0(); MFMA_Q(0, 0); BAR();
        // P6
        READ_A(1, 4); READ_B(1, 2); stage_half(t1 + 1, 3, 0);
        BAR(); LGKM0(); MFMA_Q(0, 2); BAR();
        // P7 (buf1 free: stage next-odd tile)
        stage_half(t1 + 2, 0, 1);
        BAR(); MFMA_Q(4, 0); BAR();
        // P8
        stage_half(t1 + 2, 1, 1);
        BAR(); MFMA_Q(4, 2); VM4(); BAR();   // tile 2j+2 fully landed
    }

    // epilogue
#pragma unroll
    for (int f = 0; f < 8; ++f)
#pragma unroll
        for (int g = 0; g < 4; ++g)
#pragma unroll
            for (int r = 0; r < 4; ++r) {
                int row = m0 + wm * 128 + f * 16 + hi * 4 + r;
                int col = n0 + wn * 64 + g * 16 + li;
                store_out(C + (size_t)row * N + col, acc[f][g][r]);
            }
}

// ---------------------------------------------------------------- RoPE (+scale on q)
// One thread per (b*t, d); loops over the 16 heads (angle is head-independent).
// Native v_exp/v_sin/v_cos in revolutions. q pre-scale folds 1/sqrt(128)*log2e.
__global__ __launch_bounds__(256) void rope_qk(bf16* __restrict__ q, bf16* __restrict__ k) {
    int idx = blockIdx.x * blockDim.x + threadIdx.x;  // B*T*64 total
    int d = idx & 63;
    int bt = idx >> 6;
    int tpos = bt & 2047;
    // freq/(2pi) = 2^(-d*log2(10000)/64) / (2pi)
    float frev = exp2_fast((float)d * -0.20762051f) * 0.15915494f;
    float rev = (float)tpos * frev;
    rev -= floorf(rev);
    float s = sin2pi(rev), c = cos2pi(rev);
    const float scale_q = 0.12751682f;            // (1/sqrt(128)) * log2(e)
    size_t base0 = (size_t)bt * 2048 + d;
#pragma unroll 4
    for (int h = 0; h < 16; ++h) {
        size_t base = base0 + h * 128;
        {
            float x1 = __bfloat162float(q[base]);
            float x2 = __bfloat162float(q[base + 64]);
            q[base]      = __float2bfloat16((x1 * c - x2 * s) * scale_q);
            q[base + 64] = __float2bfloat16((x1 * s + x2 * c) * scale_q);
        }
        {
            float x1 = __bfloat162float(k[base]);
            float x2 = __bfloat162float(k[base + 64]);
            k[base]      = __float2bfloat16(x1 * c - x2 * s);
            k[base + 64] = __float2bfloat16(x1 * s + x2 * c);
        }
    }
}

// ---------------------------------------------------------------- V transpose
// v: [B*T][C] -> vT: [B*H][D][T]
__global__ __launch_bounds__(256) void transpose_v(const bf16* __restrict__ v,
                                                   bf16* __restrict__ vT) {
    __shared__ bf16 tile[64][65];
    const int T = 2048, Cc = 2048;
    int bh = blockIdx.z, b = bh >> 4, h = bh & 15;
    int t0 = blockIdx.x * 64, d0 = blockIdx.y * 64;
    int tx = threadIdx.x & 63, ty = threadIdx.x >> 6;
#pragma unroll
    for (int i = 0; i < 16; i++) {
        int tt = ty + i * 4;
        tile[tt][tx] = v[(size_t)(b * T + t0 + tt) * Cc + h * 128 + d0 + tx];
    }
    __syncthreads();
#pragma unroll
    for (int i = 0; i < 16; i++) {
        int dd = ty + i * 4;
        vT[(size_t)(bh * 128 + d0 + dd) * T + t0 + tx] = tile[tx][dd];
    }
}

// ---------------------------------------------------------------- flash attention
// q,k: [B*T][C] bf16 (rope'd; q pre-scaled incl. log2e -> base-2 softmax).
// vT: [B*H][D][T]. att out: [B*T][C] bf16. grid: (16 pairs, B*H); each block
// does q-blocks {pair, 31-pair} = 33 KV-tiles -> perfect balance.
// Softmax: diagonal-only masking, defer-max (THR=8) skips most rescales,
// l-sum reduced once in the epilogue (linear in tiles).
__global__ __launch_bounds__(256) void flash_attn(const bf16* __restrict__ q,
                                                  const bf16* __restrict__ k,
                                                  const bf16* __restrict__ vT,
                                                  bf16* __restrict__ att) {
    const int T = 2048, Cc = 2048;
    __shared__ bf16 Ks[64 * 128];    // [kv row][d], 256B rows, swizzled
    __shared__ bf16 VTs[128 * 64];   // [d][kv row], 128B rows, swizzled
    __shared__ bf16 Ps[4][16 * 72];  // per-wave P tile, stride 72 elems (144B)
    const int t = threadIdx.x, lane = t & 63, w = t >> 6;
    const int bh = blockIdx.y, b = bh >> 4, h = bh & 15;
    const int col = lane & 15, hi = lane >> 4;

    for (int pass = 0; pass < 2; ++pass) {
        const int qblk = pass ? (31 - (int)blockIdx.x) : (int)blockIdx.x;
        const int q0 = qblk * 64;

        bf16x8_t qf[4];
        {
            int qrow = q0 + w * 16 + col;
            const char* qb = (const char*)q + ((size_t)(b * T + qrow) * Cc + h * 128) * 2;
#pragma unroll
            for (int kf = 0; kf < 4; kf++)
                qf[kf] = *reinterpret_cast<const bf16x8_t*>(qb + kf * 64 + hi * 16);
        }

        f32x4_t acc[8];
#pragma unroll
        for (int i = 0; i < 8; i++) acc[i] = f32x4_t{0.f, 0.f, 0.f, 0.f};
        float m_run[4] = {-1e30f, -1e30f, -1e30f, -1e30f};
        float lp[4] = {0.f, 0.f, 0.f, 0.f};   // per-lane partial row-sums

        const int ntiles = qblk + 1;  // causal
        for (int ti = 0; ti < ntiles; ++ti) {
            const int k0 = ti * 64;
#pragma unroll
            for (int i = 0; i < 4; ++i) {
                int o = (i * 256 + t) * 16;
                int kr = o >> 8, kc = (o & 255) ^ ((kr & 7) << 4);
                gload_lds16((const char*)k + ((size_t)(b * T + k0 + kr) * Cc + h * 128) * 2 + kc,
                            (char*)Ks + (i * 256 + w * 64) * 16);
                int vr = o >> 7, vc = (o & 127) ^ ((vr & 7) << 4);
                gload_lds16((const char*)vT + ((size_t)(bh * 128 + vr) * T + k0) * 2 + vc,
                            (char*)VTs + (i * 256 + w * 64) * 16);
            }
            __syncthreads();

            // S = q @ k^T  (16 rows x 64 cols per wave), base-2 domain
            f32x4_t s[4];
            __builtin_amdgcn_s_setprio(1);
#pragma unroll
            for (int nb = 0; nb < 4; nb++) {
                s[nb] = f32x4_t{0.f, 0.f, 0.f, 0.f};
#pragma unroll
                for (int kf = 0; kf < 4; kf++) {
                    bf16x8_t kfr = *reinterpret_cast<const bf16x8_t*>(
                        (const char*)Ks + (((nb * 16 + col) * 256 + kf * 64 + hi * 16)
                                           ^ ((col & 7) << 4)));
                    s[nb] = mfma16(qf[kf], kfr, s[nb]);
                }
            }
            __builtin_amdgcn_s_setprio(0);

            // tile row-max (mask only the diagonal tile; wave-uniform branch)
            const int rowb = q0 + w * 16 + (hi << 2);
            float mt[4] = {-1e30f, -1e30f, -1e30f, -1e30f};
            if (ti == qblk) {
#pragma unroll
                for (int nb = 0; nb < 4; nb++) {
                    int kc = k0 + nb * 16 + col;
#pragma unroll
                    for (int r = 0; r < 4; r++) {
                        float v = s[nb][r];
                        if (kc > rowb + r) v = -1e30f;
                        s[nb][r] = v;
                        mt[r] = fmaxf(mt[r], v);
                    }
                }
            } else {
#pragma unroll
                for (int nb = 0; nb < 4; nb++)
#pragma unroll
                    for (int r = 0; r < 4; r++) mt[r] = fmaxf(mt[r], s[nb][r]);
            }
#pragma unroll
            for (int r = 0; r < 4; r++) {
#pragma unroll
                for (int mk = 1; mk < 16; mk <<= 1)
                    mt[r] = fmaxf(mt[r], __shfl_xor(mt[r], mk, 64));
            }

            // defer-max: rescale only if some row grew past THR=8 (base-2: P<=256)
            float need = -1e30f;
#pragma unroll
            for (int r = 0; r < 4; r++) need = fmaxf(need, mt[r] - m_run[r]);
            if (__any(need > 8.f)) {
                float alpha[4];
#pragma unroll
                for (int r = 0; r < 4; r++) {
                    float mn = fmaxf(m_run[r], mt[r]);
                    alpha[r] = exp2_fast(m_run[r] - mn);
                    m_run[r] = mn;
                    lp[r] *= alpha[r];
                }
#pragma unroll
                for (int i = 0; i < 8; i++)
#pragma unroll
                    for (int r = 0; r < 4; r++) acc[i][r] *= alpha[r];
            }

            // P = 2^(s - m); accumulate per-lane partial sums only
#pragma unroll
            for (int nb = 0; nb < 4; nb++)
#pragma unroll
                for (int r = 0; r < 4; r++) {
                    float p = exp2_fast(s[nb][r] - m_run[r]);
                    s[nb][r] = p;
                    lp[r] += p;
                }

            // P (C/D layout) -> LDS (stride 72) -> A-operand layout
#pragma unroll
            for (int nb = 0; nb < 4; nb++)
#pragma unroll
                for (int r = 0; r < 4; r++)
                    Ps[w][((hi << 2) + r) * 72 + nb * 16 + col] =
                        __float2bfloat16(s[nb][r]);
            asm volatile("s_waitcnt lgkmcnt(0)" ::: "memory");
            __builtin_amdgcn_sched_barrier(0);
            bf16x8_t pf[2];
#pragma unroll
            for (int kb = 0; kb < 2; kb++)
                pf[kb] = *reinterpret_cast<const bf16x8_t*>(
                    (const char*)Ps[w] + col * 144 + kb * 64 + hi * 16);

            // O += P @ V
            __builtin_amdgcn_s_setprio(1);
#pragma unroll
            for (int db = 0; db < 8; db++)
#pragma unroll
                for (int kb = 0; kb < 2; kb++) {
                    bf16x8_t vf = *reinterpret_cast<const bf16x8_t*>(
                        (const char*)VTs + (((db * 16 + col) * 128 + kb * 64 + hi * 16)
                                            ^ ((col & 7) << 4)));
                    acc[db] = mfma16(pf[kb], vf, acc[db]);
                }
            __builtin_amdgcn_s_setprio(0);
            __syncthreads();
        }

        // epilogue: single l reduction + normalize + write
#pragma unroll
        for (int r = 0; r < 4; r++) {
#pragma unroll
            for (int mk = 1; mk < 16; mk <<= 1)
                lp[r] += __shfl_xor(lp[r], mk, 64);
        }
#pragma unroll
        for (int r = 0; r < 4; r++) {
            float inv = 1.0f / lp[r];
            int row = q0 + w * 16 + (hi << 2) + r;
            size_t base = (size_t)(b * T + row) * Cc + h * 128;
#pragma unroll
            for (int db = 0; db < 8; db++)
                att[base + db * 16 + col] = __float2bfloat16(acc[db][r] * inv);
        }
    }
}

// ---------------------------------------------------------------- launcher
extern "C" void kernel_launch(void* const* d_in, const int* in_sizes, int n_in,
                              void* d_out, int out_size, void* d_ws, size_t ws_size,
                              hipStream_t stream) {
    const int B = 4, T = 2048, C = 2048;
    const int M = B * T;  // 8192
    const float* x  = (const float*)d_in[0];
    const float* wq = (const float*)d_in[1];
    const float* wk = (const float*)d_in[2];
    const float* wv = (const float*)d_in[3];
    const float* wo = (const float*)d_in[4];
    float* out = (float*)d_out;

    char* ws = (char*)d_ws;
    const size_t SZ_X = (size_t)M * C * 2;       // 33554432
    const size_t SZ_W = (size_t)C * C * 2;       // 8388608
    bf16* xb   = (bf16*)(ws);
    bf16* wqb  = (bf16*)(ws + SZ_X);             // wq,wk,wv,wo contiguous
    bf16* qb   = (bf16*)(ws + SZ_X + 4 * SZ_W);
    bf16* kb   = (bf16*)(ws + 2 * SZ_X + 4 * SZ_W);
    bf16* vb   = (bf16*)(ws + 3 * SZ_X + 4 * SZ_W);
    bf16* vTb  = (bf16*)(ws + 4 * SZ_X + 4 * SZ_W);
    bf16* attb = (bf16*)(ws + 5 * SZ_X + 4 * SZ_W);
    bf16* wkb = wqb + (size_t)C * C;
    bf16* wvb = wkb + (size_t)C * C;
    bf16* wob = wvb + (size_t)C * C;

    // 1) casts
    cast_f32_bf16<<<2048, 256, 0, stream>>>(x, xb, M * C / 4);
    cast_w4<<<2048, 256, 0, stream>>>(wq, wk, wv, wo, wqb);

    // 2) QKV projections (256 blocks = (8192/256)*(2048/256), one per CU)
    const int nblk = (M / 256) * (C / 256);
    gemm_nt256<bf16><<<nblk, 512, 0, stream>>>(xb, wqb, qb, M, C, C);
    gemm_nt256<bf16><<<nblk, 512, 0, stream>>>(xb, wkb, kb, M, C, C);
    gemm_nt256<bf16><<<nblk, 512, 0, stream>>>(xb, wvb, vb, M, C, C);

    // 3) RoPE + scale (q gets 1/sqrt(d) * log2e), one thread per (bt,d)
    rope_qk<<<(B * T * 64) / 256, 256, 0, stream>>>(qb, kb);

    // 4) V transpose
    transpose_v<<<dim3(T / 64, 2, B * 16), 256, 0, stream>>>(vb, vTb);

    // 5) flash attention (paired q-blocks: uniform 33 tiles/block)
    flash_attn<<<dim3(16, B * 16), 256, 0, stream>>>(qb, kb, vTb, attb);

    // 6) output projection (fp32 out)
    gemm_nt256<float><<<nblk, 512, 0, stream>>>(attb, wob, out, M, C, C);
}